// Round 1
// baseline (4609.247 us; speedup 1.0000x reference)
//
#include <hip/hip_runtime.h>
#include <math.h>

#define N_NODES 10000
#define N_EDGES 160000

// ---------------- workspace offsets (floats) ----------------
#define OFF_PREW0T   0u          // [288][96]
#define OFF_PREW1T   27648u      // [144][48]
#define OFF_PREW2T   34560u      // [72][24]
#define OFF_WL0T     36288u      // 7 x [96][96]
#define OFF_WL1T     100800u     // 7 x [48][48]
#define OFF_WL2T     116928u     // 7 x [24][24]
#define OFF_QKW1T    120960u     // 2 x [96][64]
#define OFF_QKW2T    133248u     // 2 x [64][64]
#define OFF_AW1T     141440u     // [64][64]
#define OFF_AW2T     145536u     // [64][64]
#define OFF_AW3T     149632u     // [64][4]
#define OFF_RW1T     149888u     // [64][64]
#define OFF_RW2T     153984u     // [64][168]
#define OFF_NODE_S   164736u     // [N][96]   equiv_ln'd node scalars
#define OFF_NODE_V1  1124736u    // [N][3][48] equiv_ln'd node v1, m-major
#define OFF_NODE_V2  2564736u    // [N][5][24]
#define OFF_QNODE    3764736u    // [N][64]
#define OFF_KNODE    4404736u    // [N][64]
#define OFF_ALPHA    5044736u    // [E][4]
#define OFF_H1       5684736u    // [E][64]  silu(ele@rW1+rb1)
#define OFF_NODEMSG  15924736u   // [N][360] atomic accumulator
// total = 19,524,736 floats = 78.1 MB

__device__ __forceinline__ float siluf(float x) { return x / (1.f + expf(-x)); }

// out[o0..o0+3][e0..e0+3] += W^T slice * x ; w points at Wt[0][o0] (row stride O),
// x points at x_lds[0][e0] (row stride 32).
__device__ __forceinline__ void gemm44(float (&acc)[4][4],
    const float* __restrict__ w, const int O,
    const float* __restrict__ x, const int C)
{
#pragma unroll 2
  for (int c = 0; c < C; ++c) {
    const float4 wv = *reinterpret_cast<const float4*>(w + (size_t)c * (size_t)O);
    const float4 xv = *reinterpret_cast<const float4*>(x + ((size_t)c << 5));
    acc[0][0] = fmaf(wv.x, xv.x, acc[0][0]);
    acc[0][1] = fmaf(wv.x, xv.y, acc[0][1]);
    acc[0][2] = fmaf(wv.x, xv.z, acc[0][2]);
    acc[0][3] = fmaf(wv.x, xv.w, acc[0][3]);
    acc[1][0] = fmaf(wv.y, xv.x, acc[1][0]);
    acc[1][1] = fmaf(wv.y, xv.y, acc[1][1]);
    acc[1][2] = fmaf(wv.y, xv.z, acc[1][2]);
    acc[1][3] = fmaf(wv.y, xv.w, acc[1][3]);
    acc[2][0] = fmaf(wv.z, xv.x, acc[2][0]);
    acc[2][1] = fmaf(wv.z, xv.y, acc[2][1]);
    acc[2][2] = fmaf(wv.z, xv.z, acc[2][2]);
    acc[2][3] = fmaf(wv.z, xv.w, acc[2][3]);
    acc[3][0] = fmaf(wv.w, xv.x, acc[3][0]);
    acc[3][1] = fmaf(wv.w, xv.y, acc[3][1]);
    acc[3][2] = fmaf(wv.w, xv.z, acc[3][2]);
    acc[3][3] = fmaf(wv.w, xv.w, acc[3][3]);
  }
}

// ---------------- weight transposes ----------------
__global__ __launch_bounds__(256) void k_prep(
    const float* preW0, const float* preW1, const float* preW2,
    const float* Wl0, const float* Wl1, const float* Wl2,
    const float* qkW1, const float* qkW2,
    const float* aW1, const float* aW2, const float* aW3,
    const float* rW1, const float* rW2, float* ws)
{
  int j = blockIdx.x;
  const float* src; float* dst; int O, C;
  if (j == 0)      { src = preW0; dst = ws + OFF_PREW0T; O = 96;  C = 288; }
  else if (j == 1) { src = preW1; dst = ws + OFF_PREW1T; O = 48;  C = 144; }
  else if (j == 2) { src = preW2; dst = ws + OFF_PREW2T; O = 24;  C = 72;  }
  else if (j < 10) { int k = j-3;  src = Wl0 + k*9216; dst = ws + OFF_WL0T + k*9216; O = 96; C = 96; }
  else if (j < 17) { int k = j-10; src = Wl1 + k*2304; dst = ws + OFF_WL1T + k*2304; O = 48; C = 48; }
  else if (j < 24) { int k = j-17; src = Wl2 + k*576;  dst = ws + OFF_WL2T + k*576;  O = 24; C = 24; }
  else if (j < 26) { int k = j-24; src = qkW1 + k*6144; dst = ws + OFF_QKW1T + k*6144; O = 64; C = 96; }
  else if (j < 28) { int k = j-26; src = qkW2 + k*4096; dst = ws + OFF_QKW2T + k*4096; O = 64; C = 64; }
  else if (j == 28){ src = aW1; dst = ws + OFF_AW1T; O = 64; C = 64; }
  else if (j == 29){ src = aW2; dst = ws + OFF_AW2T; O = 64; C = 64; }
  else if (j == 30){ src = aW3; dst = ws + OFF_AW3T; O = 4;  C = 64; }
  else if (j == 31){ src = rW1; dst = ws + OFF_RW1T; O = 64; C = 64; }
  else             { src = rW2; dst = ws + OFF_RW2T; O = 168; C = 64; }
  int tot = O * C;
  for (int idx = threadIdx.x; idx < tot; idx += 256) {
    int o = idx / C, c = idx % C;
    dst[c*O + o] = src[idx];
  }
}

// ---------------- node kernel: equiv_ln + q/k mlp2 ----------------
__global__ __launch_bounds__(256) void k_node(
    const float* __restrict__ node_fea,
    const float* __restrict__ ln_w0, const float* __restrict__ ln_b0,
    const float* __restrict__ ln_w1, const float* __restrict__ ln_w2,
    const float* __restrict__ qk_b1, const float* __restrict__ qk_lnw,
    const float* __restrict__ qk_lnb, const float* __restrict__ qk_b2,
    float* __restrict__ ws)
{
  __shared__ __align__(16) float sbuf[96*32];
  __shared__ __align__(16) float vbuf[3*48*32];
  __shared__ float statA[32], statB[32];
  const int t = threadIdx.x;
  const int lane_e = t & 31, g = t >> 5;
  const int n0 = blockIdx.x * 32;
  const int n = n0 + lane_e;
  const bool valid = n < N_NODES;
  const int eq = t & 7, oc = t >> 3, e0 = 4*eq, o0 = 4*oc;

  // --- scalars: stage transposed [c][e]
  for (int k = 0; k < 3; ++k) {
    int q = g + 8*k;
    float4 v = valid ? *(const float4*)(node_fea + (size_t)n*360 + 4*q)
                     : make_float4(0.f,0.f,0.f,0.f);
    sbuf[(4*q+0)*32+lane_e] = v.x; sbuf[(4*q+1)*32+lane_e] = v.y;
    sbuf[(4*q+2)*32+lane_e] = v.z; sbuf[(4*q+3)*32+lane_e] = v.w;
  }
  __syncthreads();
  if (t < 32 && valid) {
    float s = 0.f;
    for (int c = 0; c < 96; ++c) s += sbuf[c*32+t];
    float mu = s / 96.f, ss = 0.f;
    for (int c = 0; c < 96; ++c) { float x = sbuf[c*32+t]-mu; ss += x*x; }
    statA[t] = mu; statB[t] = rsqrtf(ss/96.f + 1e-5f);
  }
  __syncthreads();
  for (int idx = t; idx < 96*32; idx += 256) {
    int c = idx >> 5, e = idx & 31;
    sbuf[idx] = (sbuf[idx]-statA[e])*statB[e]*ln_w0[c] + ln_b0[c];
  }
  __syncthreads();
  for (int k = 0; k < 3; ++k) {   // write node_s
    int q = g + 8*k;
    if (valid) {
      float4 v = { sbuf[(4*q+0)*32+lane_e], sbuf[(4*q+1)*32+lane_e],
                   sbuf[(4*q+2)*32+lane_e], sbuf[(4*q+3)*32+lane_e] };
      *(float4*)(ws + OFF_NODE_S + (size_t)n*96 + 4*q) = v;
    }
  }
  // --- q (p=0, uses edge_dst downstream) and k (p=1) mlp2
  for (int p = 0; p < 2; ++p) {
    if (oc < 16) {
      float acc[4][4] = {};
      gemm44(acc, ws + OFF_QKW1T + p*6144 + o0, 64, sbuf + e0, 96);
      for (int i = 0; i < 4; ++i) {
        float b = qk_b1[p*64 + o0 + i];
        for (int jj = 0; jj < 4; ++jj) vbuf[(o0+i)*32 + e0+jj] = acc[i][jj] + b;
      }
    }
    __syncthreads();
    if (t < 32 && valid) {
      float s = 0.f;
      for (int c = 0; c < 64; ++c) s += vbuf[c*32+t];
      float mu = s/64.f, ss = 0.f;
      for (int c = 0; c < 64; ++c) { float x = vbuf[c*32+t]-mu; ss += x*x; }
      statA[t] = mu; statB[t] = rsqrtf(ss/64.f + 1e-6f);
    }
    __syncthreads();
    for (int idx = t; idx < 64*32; idx += 256) {
      int c = idx >> 5, e = idx & 31;
      float x = (vbuf[idx]-statA[e])*statB[e]*qk_lnw[p*64+c] + qk_lnb[p*64+c];
      vbuf[idx] = siluf(x);
    }
    __syncthreads();
    if (oc < 16) {
      float acc[4][4] = {};
      gemm44(acc, ws + OFF_QKW2T + p*4096 + o0, 64, vbuf + e0, 64);
      size_t base = (p == 0) ? OFF_QNODE : OFF_KNODE;
      for (int jj = 0; jj < 4; ++jj) {
        int n2 = n0 + e0 + jj;
        if (n2 < N_NODES) {
          float4 v = { acc[0][jj]+qk_b2[p*64+o0+0], acc[1][jj]+qk_b2[p*64+o0+1],
                       acc[2][jj]+qk_b2[p*64+o0+2], acc[3][jj]+qk_b2[p*64+o0+3] };
          *(float4*)(ws + base + (size_t)n2*64 + o0) = v;
        }
      }
    }
    __syncthreads();
  }
  // --- v1: stage [m][c][e]
  for (int k = 0; k < 5; ++k) {
    int q = g + 8*k;
    if (q < 36) {
      float4 v = valid ? *(const float4*)(node_fea + (size_t)n*360 + 96 + 4*q)
                       : make_float4(0.f,0.f,0.f,0.f);
      float vv[4] = {v.x, v.y, v.z, v.w};
      for (int i = 0; i < 4; ++i) {
        int f = 4*q+i; vbuf[((f%3)*48 + f/3)*32 + lane_e] = vv[i];
      }
    }
  }
  __syncthreads();
  if (t < 32 && valid) {
    float ss = 0.f;
    for (int row = 0; row < 144; ++row) { float x = vbuf[row*32+t]; ss += x*x; }
    statB[t] = rsqrtf(ss/48.f + 1e-5f);
  }
  __syncthreads();
  for (int idx = t; idx < 144*32; idx += 256) {
    int row = idx >> 5, e = idx & 31;
    vbuf[idx] *= statB[e]*ln_w1[row % 48];
  }
  __syncthreads();
  for (int k = 0; k < 5; ++k) {
    int q = g + 8*k;
    if (q < 36 && valid) {
      float4 v = { vbuf[(4*q+0)*32+lane_e], vbuf[(4*q+1)*32+lane_e],
                   vbuf[(4*q+2)*32+lane_e], vbuf[(4*q+3)*32+lane_e] };
      *(float4*)(ws + OFF_NODE_V1 + (size_t)n*144 + 4*q) = v;
    }
  }
  __syncthreads();
  // --- v2: stage [m][c][e]
  for (int k = 0; k < 4; ++k) {
    int q = g + 8*k;
    if (q < 30) {
      float4 v = valid ? *(const float4*)(node_fea + (size_t)n*360 + 240 + 4*q)
                       : make_float4(0.f,0.f,0.f,0.f);
      float vv[4] = {v.x, v.y, v.z, v.w};
      for (int i = 0; i < 4; ++i) {
        int f = 4*q+i; vbuf[((f%5)*24 + f/5)*32 + lane_e] = vv[i];
      }
    }
  }
  __syncthreads();
  if (t < 32 && valid) {
    float ss = 0.f;
    for (int row = 0; row < 120; ++row) { float x = vbuf[row*32+t]; ss += x*x; }
    statB[t] = rsqrtf(ss/24.f + 1e-5f);
  }
  __syncthreads();
  for (int idx = t; idx < 120*32; idx += 256) {
    int row = idx >> 5, e = idx & 31;
    vbuf[idx] *= statB[e]*ln_w2[row % 24];
  }
  __syncthreads();
  for (int k = 0; k < 4; ++k) {
    int q = g + 8*k;
    if (q < 30 && valid) {
      float4 v = { vbuf[(4*q+0)*32+lane_e], vbuf[(4*q+1)*32+lane_e],
                   vbuf[(4*q+2)*32+lane_e], vbuf[(4*q+3)*32+lane_e] };
      *(float4*)(ws + OFF_NODE_V2 + (size_t)n*120 + 4*q) = v;
    }
  }
}

// ---------------- per-edge: alpha + h1 (radial hidden) ----------------
__global__ __launch_bounds__(256) void k_alpha(
    const float* __restrict__ ele, const float* __restrict__ r_b1,
    const float* __restrict__ a_b1, const float* __restrict__ a_ln1w, const float* __restrict__ a_ln1b,
    const float* __restrict__ a_b2, const float* __restrict__ a_ln2w, const float* __restrict__ a_ln2b,
    const float* __restrict__ a_b3,
    const int* __restrict__ edge_src, const int* __restrict__ edge_dst,
    float* __restrict__ ws)
{
  __shared__ __align__(16) float eb[64*32];
  __shared__ __align__(16) float hb[64*32];
  __shared__ float statA[32], statB[32];
  __shared__ int srcs[32], dsts[32];
  const int t = threadIdx.x, lane_e = t & 31, g = t >> 5;
  const int e0base = blockIdx.x * 32;
  const int eq = t & 7, oc = t >> 3, e0 = 4*eq, o0 = 4*oc;
  if (t < 32) { srcs[t] = edge_src[e0base+t]; dsts[t] = edge_dst[e0base+t]; }
  for (int k = 0; k < 2; ++k) {
    int q = g + 8*k;
    float4 v = *(const float4*)(ele + (size_t)(e0base+lane_e)*64 + 4*q);
    eb[(4*q+0)*32+lane_e] = v.x; eb[(4*q+1)*32+lane_e] = v.y;
    eb[(4*q+2)*32+lane_e] = v.z; eb[(4*q+3)*32+lane_e] = v.w;
  }
  __syncthreads();
  if (oc < 16) {
    // h1 for radial -> ws
    float acc[4][4] = {};
    gemm44(acc, ws + OFF_RW1T + o0, 64, eb + e0, 64);
    for (int jj = 0; jj < 4; ++jj) {
      float4 v = { siluf(acc[0][jj]+r_b1[o0+0]), siluf(acc[1][jj]+r_b1[o0+1]),
                   siluf(acc[2][jj]+r_b1[o0+2]), siluf(acc[3][jj]+r_b1[o0+3]) };
      *(float4*)(ws + OFF_H1 + (size_t)(e0base+e0+jj)*64 + o0) = v;
    }
    // attention mlp layer 1
    float acc2[4][4] = {};
    gemm44(acc2, ws + OFF_AW1T + o0, 64, eb + e0, 64);
    for (int i = 0; i < 4; ++i) {
      float b = a_b1[o0+i];
      for (int jj = 0; jj < 4; ++jj) hb[(o0+i)*32 + e0+jj] = acc2[i][jj] + b;
    }
  }
  __syncthreads();
  if (t < 32) {
    float s = 0.f;
    for (int c = 0; c < 64; ++c) s += hb[c*32+t];
    float mu = s/64.f, ss = 0.f;
    for (int c = 0; c < 64; ++c) { float x = hb[c*32+t]-mu; ss += x*x; }
    statA[t] = mu; statB[t] = rsqrtf(ss/64.f + 1e-6f);
  }
  __syncthreads();
  for (int idx = t; idx < 64*32; idx += 256) {
    int c = idx >> 5, e = idx & 31;
    hb[idx] = siluf((hb[idx]-statA[e])*statB[e]*a_ln1w[c] + a_ln1b[c]);
  }
  __syncthreads();
  if (oc < 16) {
    float acc[4][4] = {};
    gemm44(acc, ws + OFF_AW2T + o0, 64, hb + e0, 64);
    for (int i = 0; i < 4; ++i) {
      float b = a_b2[o0+i];
      for (int jj = 0; jj < 4; ++jj) eb[(o0+i)*32 + e0+jj] = acc[i][jj] + b;
    }
  }
  __syncthreads();
  if (t < 32) {
    float s = 0.f;
    for (int c = 0; c < 64; ++c) s += eb[c*32+t];
    float mu = s/64.f, ss = 0.f;
    for (int c = 0; c < 64; ++c) { float x = eb[c*32+t]-mu; ss += x*x; }
    statA[t] = mu; statB[t] = rsqrtf(ss/64.f + 1e-6f);
  }
  __syncthreads();
  for (int idx = t; idx < 64*32; idx += 256) {
    int c = idx >> 5, e = idx & 31;
    eb[idx] = siluf((eb[idx]-statA[e])*statB[e]*a_ln2w[c] + a_ln2b[c]);
  }
  __syncthreads();
  if (t < 32) {
    float h3[4] = { a_b3[0], a_b3[1], a_b3[2], a_b3[3] };
    for (int c = 0; c < 64; ++c) {
      float x = eb[c*32+t];
      h3[0] = fmaf(x, ws[OFF_AW3T + c*4+0], h3[0]);
      h3[1] = fmaf(x, ws[OFF_AW3T + c*4+1], h3[1]);
      h3[2] = fmaf(x, ws[OFF_AW3T + c*4+2], h3[2]);
      h3[3] = fmaf(x, ws[OFF_AW3T + c*4+3], h3[3]);
    }
    const float* qp = ws + OFF_QNODE + (size_t)dsts[t]*64;
    const float* kp = ws + OFF_KNODE + (size_t)srcs[t]*64;
    float qk[4] = {0.f,0.f,0.f,0.f};
    for (int j = 0; j < 16; ++j) {
      float4 qv = *(const float4*)(qp + 4*j);
      float4 kv = *(const float4*)(kp + 4*j);
      qk[j>>2] += qv.x*kv.x + qv.y*kv.y + qv.z*kv.z + qv.w*kv.w;
    }
    float4 outv = { qk[0]*0.25f + h3[0], qk[1]*0.25f + h3[1],
                    qk[2]*0.25f + h3[2], qk[3]*0.25f + h3[3] };
    *(float4*)(ws + OFF_ALPHA + (size_t)(e0base+t)*4) = outv;
  }
}

// ---------------- scalar chain ----------------
__global__ __launch_bounds__(256) void k_sc(
    const float* __restrict__ edge_fea, const float* __restrict__ edge_vec,
    const float* __restrict__ ln_w0, const float* __restrict__ ln_b0,
    const float* __restrict__ r_b2,
    const int* __restrict__ edge_src, const int* __restrict__ edge_dst,
    float* ws, float* out)
{
  __shared__ __align__(16) float xcat[288*32];
  __shared__ __align__(16) float b1[96*32];
  __shared__ __align__(16) float b2[96*32];
  __shared__ __align__(16) float als[32*4];
  __shared__ float statA[32], statB[32];
  __shared__ int srcs[32], dsts[32], flags[32];
  const int t = threadIdx.x, lane_e = t & 31, g = t >> 5;
  const int e0base = blockIdx.x * 32;
  const int eq = t & 7, oc = t >> 3, e0 = 4*eq, o0 = 4*oc;
  if (t < 32) {
    srcs[t] = edge_src[e0base+t]; dsts[t] = edge_dst[e0base+t];
    float vx = edge_vec[(e0base+t)*3+0], vy = edge_vec[(e0base+t)*3+1], vz = edge_vec[(e0base+t)*3+2];
    flags[t] = (vx*vx + vy*vy + vz*vz) < 1e-20f ? 1 : 0;
  }
  if (t >= 32 && t < 64) {
    int e = t - 32;
    *(float4*)(als + e*4) = *(const float4*)(ws + OFF_ALPHA + (size_t)(e0base+e)*4);
  }
  // h1 into xcat[0:2048]
  for (int k = 0; k < 2; ++k) {
    int q = g + 8*k;
    float4 v = *(const float4*)(ws + OFF_H1 + (size_t)(e0base+lane_e)*64 + 4*q);
    xcat[(4*q+0)*32+lane_e] = v.x; xcat[(4*q+1)*32+lane_e] = v.y;
    xcat[(4*q+2)*32+lane_e] = v.z; xcat[(4*q+3)*32+lane_e] = v.w;
  }
  __syncthreads();
  float rad[4][4];
  if (oc < 24) {
    float acc[4][4] = {};
    gemm44(acc, ws + OFF_RW2T + o0, 168, xcat + e0, 64);
    for (int i = 0; i < 4; ++i) {
      float b = r_b2[o0+i];
      for (int jj = 0; jj < 4; ++jj) rad[i][jj] = acc[i][jj] + b;
    }
  }
  __syncthreads();
  // stage xcat: [0..95]=node_s[src], [96..191]=node_s[dst], [192..287]=raw edge_fea s
  {
    const float* sp = ws + OFF_NODE_S + (size_t)srcs[lane_e]*96;
    const float* dp = ws + OFF_NODE_S + (size_t)dsts[lane_e]*96;
    const float* ep = edge_fea + (size_t)(e0base+lane_e)*360;
    for (int k = 0; k < 3; ++k) {
      int q = g + 8*k;
      float4 a = *(const float4*)(sp + 4*q);
      float4 b = *(const float4*)(dp + 4*q);
      float4 c = *(const float4*)(ep + 4*q);
      float av[4] = {a.x,a.y,a.z,a.w}, bv[4] = {b.x,b.y,b.z,b.w}, cv[4] = {c.x,c.y,c.z,c.w};
      for (int i = 0; i < 4; ++i) {
        xcat[(4*q+i)*32 + lane_e]        = av[i];
        xcat[(96+4*q+i)*32 + lane_e]     = bv[i];
        xcat[(192+4*q+i)*32 + lane_e]    = cv[i];
      }
    }
  }
  __syncthreads();
  // equiv_ln (params row 1) on edge part
  if (t < 32) {
    float s = 0.f;
    for (int c = 0; c < 96; ++c) s += xcat[(192+c)*32+t];
    float mu = s/96.f, ss = 0.f;
    for (int c = 0; c < 96; ++c) { float x = xcat[(192+c)*32+t]-mu; ss += x*x; }
    statA[t] = mu; statB[t] = rsqrtf(ss/96.f + 1e-5f);
  }
  __syncthreads();
  for (int idx = t; idx < 96*32; idx += 256) {
    int c = idx >> 5, e = idx & 31;
    xcat[(192+c)*32+e] = (xcat[(192+c)*32+e]-statA[e])*statB[e]*ln_w0[96+c] + ln_b0[96+c];
  }
  __syncthreads();
  // message GEMM (preW0) -> b1
  if (oc < 24) {
    float acc[4][4] = {};
    gemm44(acc, ws + OFF_PREW0T + o0, 96, xcat + e0, 288);
    for (int i = 0; i < 4; ++i)
      for (int jj = 0; jj < 4; ++jj) b1[(o0+i)*32 + e0+jj] = acc[i][jj];
  }
  __syncthreads();
  // so2#1: GEMM Wl0[0] * radial -> b2
  if (oc < 24) {
    float acc[4][4] = {};
    gemm44(acc, ws + OFF_WL0T + 0*9216 + o0, 96, b1 + e0, 96);
    for (int i = 0; i < 4; ++i)
      for (int jj = 0; jj < 4; ++jj) b2[(o0+i)*32 + e0+jj] = acc[i][jj]*rad[i][jj];
  }
  __syncthreads();
  // equiv_ln (params row 2) + silu
  if (t < 32) {
    float s = 0.f;
    for (int c = 0; c < 96; ++c) s += b2[c*32+t];
    float mu = s/96.f, ss = 0.f;
    for (int c = 0; c < 96; ++c) { float x = b2[c*32+t]-mu; ss += x*x; }
    statA[t] = mu; statB[t] = rsqrtf(ss/96.f + 1e-5f);
  }
  __syncthreads();
  for (int idx = t; idx < 96*32; idx += 256) {
    int c = idx >> 5, e = idx & 31;
    b2[idx] = siluf((b2[idx]-statA[e])*statB[e]*ln_w0[192+c] + ln_b0[192+c]);
  }
  __syncthreads();
  // so2#2 + onsite + alpha + scatter
  float sfin[4][4];
  if (oc < 24) {
    float acc[4][4] = {};
    gemm44(acc, ws + OFF_WL0T + 1*9216 + o0, 96, b2 + e0, 96);
    for (int jj = 0; jj < 4; ++jj) {
      if (flags[e0+jj]) {
        for (int i = 0; i < 4; ++i) {
          float s = 0.f;
          for (int c = 0; c < 96; ++c)
            s = fmaf(ws[OFF_WL0T + 2*9216 + c*96 + o0+i], b1[c*32 + e0+jj], s);
          acc[i][jj] = s;
        }
      }
      for (int i = 0; i < 4; ++i) {
        float v = acc[i][jj] * als[(e0+jj)*4 + (o0+i)/24];
        sfin[i][jj] = v;
        atomicAdd(ws + OFF_NODEMSG + (size_t)dsts[e0+jj]*360 + o0+i, v);
      }
    }
  }
  __syncthreads();
  if (oc < 24) {
    for (int i = 0; i < 4; ++i)
      for (int jj = 0; jj < 4; ++jj) b2[(o0+i)*32 + e0+jj] = sfin[i][jj];
  }
  // restage raw edge_fea s into b1
  {
    const float* ep = edge_fea + (size_t)(e0base+lane_e)*360;
    for (int k = 0; k < 3; ++k) {
      int q = g + 8*k;
      float4 c = *(const float4*)(ep + 4*q);
      float cv[4] = {c.x,c.y,c.z,c.w};
      for (int i = 0; i < 4; ++i) b1[(4*q+i)*32 + lane_e] = cv[i];
    }
  }
  __syncthreads();
  if (oc < 24) {
    float acc[4][4] = {};
    gemm44(acc, ws + OFF_WL0T + 4*9216 + o0, 96, b2 + e0, 96);
    gemm44(acc, ws + OFF_WL0T + 6*9216 + o0, 96, b1 + e0, 96);
    for (int jj = 0; jj < 4; ++jj) {
      float4 v = { acc[0][jj], acc[1][jj], acc[2][jj], acc[3][jj] };
      *(float4*)(out + (size_t)N_NODES*360 + (size_t)(e0base+e0+jj)*360 + o0) = v;
    }
  }
}

// ---------------- v1 chain ----------------
__global__ __launch_bounds__(256) void k_v1c(
    const float* __restrict__ edge_fea, const float* __restrict__ edge_vec,
    const float* __restrict__ D1g,
    const float* __restrict__ ln_w1, const float* __restrict__ r_b2,
    const int* __restrict__ edge_src, const int* __restrict__ edge_dst,
    float* ws, float* out)
{
  __shared__ __align__(16) float ebuf[3*48*32];   // 4608
  __shared__ __align__(16) float msgb[3*48*32];   // 4608 (h1 staging uses first 2048)
  __shared__ __align__(16) float buf2[2*96*32];   // 6144: gbuf (2x[96][32]) then rot buffers
  __shared__ float D1s[32*9], G1s[32*9];
  __shared__ __align__(16) float als[128];
  __shared__ float statB[32];
  __shared__ int srcs[32], dsts[32], flags[32];
  const int t = threadIdx.x, lane_e = t & 31, g = t >> 5;
  const int e0base = blockIdx.x * 32;
  const int eq = t & 7, r = t >> 3, e0 = 4*eq;
  if (t < 32) {
    srcs[t] = edge_src[e0base+t]; dsts[t] = edge_dst[e0base+t];
    float vx = edge_vec[(e0base+t)*3+0], vy = edge_vec[(e0base+t)*3+1], vz = edge_vec[(e0base+t)*3+2];
    flags[t] = (vx*vx + vy*vy + vz*vz) < 1e-20f ? 1 : 0;
  }
  if (t >= 32 && t < 64) {
    int e = t - 32;
    *(float4*)(als + e*4) = *(const float4*)(ws + OFF_ALPHA + (size_t)(e0base+e)*4);
  }
  for (int idx = t; idx < 288; idx += 256) D1s[idx] = D1g[(size_t)e0base*9 + idx];
  __syncthreads();
  for (int idx = t; idx < 288; idx += 256) {
    int e = idx/9, nn = (idx%9)/3, p = idx%3;
    float s = 0.f;
    for (int m = 0; m < 3; ++m) s += D1s[e*9+nn*3+m]*D1s[e*9+p*3+m];
    G1s[idx] = s;
  }
  for (int k = 0; k < 2; ++k) {   // h1 -> msgb[0:2048]
    int q = g + 8*k;
    float4 v = *(const float4*)(ws + OFF_H1 + (size_t)(e0base+lane_e)*64 + 4*q);
    msgb[(4*q+0)*32+lane_e] = v.x; msgb[(4*q+1)*32+lane_e] = v.y;
    msgb[(4*q+2)*32+lane_e] = v.z; msgb[(4*q+3)*32+lane_e] = v.w;
  }
  __syncthreads();
  float rad[4][4];
  {
    int oc12 = r % 12, o0r = 4*oc12;
    float acc[4][4] = {};
    gemm44(acc, ws + OFF_RW2T + 96 + o0r, 168, msgb + e0, 64);
    for (int i = 0; i < 4; ++i) {
      float b = r_b2[96 + o0r + i];
      for (int jj = 0; jj < 4; ++jj) rad[i][jj] = acc[i][jj] + b;
    }
  }
  __syncthreads();
  // raw edge v1 -> ebuf [m][c][e], then equiv_ln (row 1)
  {
    const float* ep = edge_fea + (size_t)(e0base+lane_e)*360 + 96;
    for (int k = 0; k < 5; ++k) {
      int q = g + 8*k;
      if (q < 36) {
        float4 v = *(const float4*)(ep + 4*q);
        float vv[4] = {v.x,v.y,v.z,v.w};
        for (int i = 0; i < 4; ++i) { int f = 4*q+i; ebuf[((f%3)*48 + f/3)*32 + lane_e] = vv[i]; }
      }
    }
  }
  __syncthreads();
  if (t < 32) {
    float ss = 0.f;
    for (int row = 0; row < 144; ++row) { float x = ebuf[row*32+t]; ss += x*x; }
    statB[t] = rsqrtf(ss/48.f + 1e-5f);
  }
  __syncthreads();
  for (int idx = t; idx < 4608; idx += 256) {
    int row = idx >> 5, e = idx & 31;
    ebuf[idx] *= statB[e]*ln_w1[48 + (row % 48)];
  }
  __syncthreads();
  // message GEMMs over m (pairs): cat = [src48, dst48 | edge48]
  for (int mb = 0; mb < 3; mb += 2) {
    for (int dm = 0; dm < 2; ++dm) {
      int m = mb + dm;
      if (m < 3) {
        const float* sp = ws + OFF_NODE_V1 + (size_t)srcs[lane_e]*144 + m*48;
        const float* dp = ws + OFF_NODE_V1 + (size_t)dsts[lane_e]*144 + m*48;
        for (int k = 0; k < 2; ++k) {
          int q = g + 8*k;
          if (q < 12) {
            float4 a = *(const float4*)(sp + 4*q);
            float4 b = *(const float4*)(dp + 4*q);
            float av[4] = {a.x,a.y,a.z,a.w}, bv[4] = {b.x,b.y,b.z,b.w};
            for (int i = 0; i < 4; ++i) {
              buf2[dm*3072 + (4*q+i)*32 + lane_e]      = av[i];
              buf2[dm*3072 + (48+4*q+i)*32 + lane_e]   = bv[i];
            }
          }
        }
      }
    }
    __syncthreads();
    {
      int oc = r % 12, dm = r / 12, m = mb + dm;
      if (r < 24 && m < 3) {
        int o0 = 4*oc;
        float acc[4][4] = {};
        gemm44(acc, ws + OFF_PREW1T + o0, 48, buf2 + dm*3072 + e0, 96);
        gemm44(acc, ws + OFF_PREW1T + 96*48 + o0, 48, ebuf + m*1536 + e0, 48);
        for (int i = 0; i < 4; ++i)
          for (int jj = 0; jj < 4; ++jj) msgb[m*1536 + (o0+i)*32 + e0+jj] = acc[i][jj];
      }
    }
    __syncthreads();
  }
  // rotate in: buf2[n][c][e] = sum_m D1[n,m]*msg[m][c][e]
  for (int idx = t; idx < 4608; idx += 256) {
    int e = idx & 31, row = idx >> 5, c = row % 48, nn = row / 48;
    float s = 0.f;
    for (int m = 0; m < 3; ++m) s = fmaf(D1s[e*9+nn*3+m], msgb[m*1536 + c*32 + e], s);
    buf2[nn*1536 + c*32 + e] = s;
  }
  __syncthreads();
  // so2#1 GEMM (Wl1[0]) * radial -> ebuf
  for (int nb = 0; nb < 3; nb += 2) {
    int oc = r % 12, dn = r / 12, nn = nb + dn;
    if (r < 24 && nn < 3) {
      int o0 = 4*oc;
      float acc[4][4] = {};
      gemm44(acc, ws + OFF_WL1T + 0*2304 + o0, 48, buf2 + nn*1536 + e0, 48);
      for (int i = 0; i < 4; ++i)
        for (int jj = 0; jj < 4; ++jj) ebuf[nn*1536 + (o0+i)*32 + e0+jj] = acc[i][jj]*rad[i][jj];
    }
  }
  __syncthreads();
  // equiv_ln v1 (row 2)
  if (t < 32) {
    float ss = 0.f;
    for (int row = 0; row < 144; ++row) { float x = ebuf[row*32+t]; ss += x*x; }
    statB[t] = rsqrtf(ss/48.f + 1e-5f);
  }
  __syncthreads();
  for (int idx = t; idx < 4608; idx += 256) {
    int row = idx >> 5, e = idx & 31;
    ebuf[idx] *= statB[e]*ln_w1[96 + (row % 48)];
  }
  __syncthreads();
  // fused middle rotation G1 = D1*D1^T
  for (int idx = t; idx < 4608; idx += 256) {
    int e = idx & 31, row = idx >> 5, c = row % 48, nn = row / 48;
    float s = 0.f;
    for (int p = 0; p < 3; ++p) s = fmaf(G1s[e*9+nn*3+p], ebuf[p*1536 + c*32 + e], s);
    buf2[nn*1536 + c*32 + e] = s;
  }
  __syncthreads();
  // so2#2 GEMM (Wl1[1]) -> ebuf
  for (int nb = 0; nb < 3; nb += 2) {
    int oc = r % 12, dn = r / 12, nn = nb + dn;
    if (r < 24 && nn < 3) {
      int o0 = 4*oc;
      float acc[4][4] = {};
      gemm44(acc, ws + OFF_WL1T + 1*2304 + o0, 48, buf2 + nn*1536 + e0, 48);
      for (int i = 0; i < 4; ++i)
        for (int jj = 0; jj < 4; ++jj) ebuf[nn*1536 + (o0+i)*32 + e0+jj] = acc[i][jj];
    }
  }
  __syncthreads();
  // rotate back D^T -> buf2 (final value)
  for (int idx = t; idx < 4608; idx += 256) {
    int e = idx & 31, row = idx >> 5, c = row % 48, nn = row / 48;
    float s = 0.f;
    for (int m = 0; m < 3; ++m) s = fmaf(D1s[e*9+m*3+nn], ebuf[m*1536 + c*32 + e], s);
    buf2[nn*1536 + c*32 + e] = s;
  }
  __syncthreads();
  // onsite + alpha + scatter ; buf2 layout row = nn*48+c
  for (int idx = t; idx < 4608; idx += 256) {
    int e = idx & 31, row = idx >> 5, c = row % 48, nn = row / 48;
    float v;
    if (flags[e]) {
      float s = 0.f;
      for (int cc = 0; cc < 48; ++cc)
        s = fmaf(ws[OFF_WL1T + 2*2304 + cc*48 + c], msgb[nn*1536 + cc*32 + e], s);
      v = s;
    } else v = buf2[idx];
    v *= als[e*4 + c/12];
    buf2[idx] = v;
    atomicAdd(ws + OFF_NODEMSG + (size_t)dsts[e]*360 + 96 + c*3 + nn, v);
  }
  __syncthreads();
  // restage RAW edge v1 -> ebuf
  {
    const float* ep = edge_fea + (size_t)(e0base+lane_e)*360 + 96;
    for (int k = 0; k < 5; ++k) {
      int q = g + 8*k;
      if (q < 36) {
        float4 v = *(const float4*)(ep + 4*q);
        float vv[4] = {v.x,v.y,v.z,v.w};
        for (int i = 0; i < 4; ++i) { int f = 4*q+i; ebuf[((f%3)*48 + f/3)*32 + lane_e] = vv[i]; }
      }
    }
  }
  __syncthreads();
  // edge_out: Wl1[4]@scaled + Wl1[6]@raw -> msgb flat [3o+n][e]
  for (int nb = 0; nb < 3; nb += 2) {
    int oc = r % 12, dn = r / 12, nn = nb + dn;
    if (r < 24 && nn < 3) {
      int o0 = 4*oc;
      float acc[4][4] = {};
      gemm44(acc, ws + OFF_WL1T + 4*2304 + o0, 48, buf2 + nn*1536 + e0, 48);
      gemm44(acc, ws + OFF_WL1T + 6*2304 + o0, 48, ebuf + nn*1536 + e0, 48);
      for (int i = 0; i < 4; ++i)
        for (int jj = 0; jj < 4; ++jj) msgb[(3*(o0+i)+nn)*32 + e0+jj] = acc[i][jj];
    }
  }
  __syncthreads();
  {
    float* op = out + (size_t)N_NODES*360 + (size_t)(e0base+lane_e)*360 + 96;
    for (int k = 0; k < 5; ++k) {
      int q = g + 8*k;
      if (q < 36) {
        float4 v = { msgb[(4*q+0)*32+lane_e], msgb[(4*q+1)*32+lane_e],
                     msgb[(4*q+2)*32+lane_e], msgb[(4*q+3)*32+lane_e] };
        *(float4*)(op + 4*q) = v;
      }
    }
  }
}

// ---------------- v2 chain ----------------
__global__ __launch_bounds__(256) void k_v2c(
    const float* __restrict__ edge_fea, const float* __restrict__ edge_vec,
    const float* __restrict__ D2g,
    const float* __restrict__ ln_w2, const float* __restrict__ r_b2,
    const int* __restrict__ edge_src, const int* __restrict__ edge_dst,
    float* ws, float* out)
{
  __shared__ __align__(16) float ebuf[5*24*32];   // 3840
  __shared__ __align__(16) float msgb[5*24*32];   // 3840 (h1 staging in first 2048)
  __shared__ __align__(16) float buf2[5*24*32];   // 3840 (gbuf 2x[48][32]=3072 fits)
  __shared__ float D2s[32*25], G2s[32*25];
  __shared__ __align__(16) float als[128];
  __shared__ float statB[32];
  __shared__ int srcs[32], dsts[32], flags[32];
  const int t = threadIdx.x, lane_e = t & 31, g = t >> 5;
  const int e0base = blockIdx.x * 32;
  const int eq = t & 7, r = t >> 3, e0 = 4*eq;
  if (t < 32) {
    srcs[t] = edge_src[e0base+t]; dsts[t] = edge_dst[e0base+t];
    float vx = edge_vec[(e0base+t)*3+0], vy = edge_vec[(e0base+t)*3+1], vz = edge_vec[(e0base+t)*3+2];
    flags[t] = (vx*vx + vy*vy + vz*vz) < 1e-20f ? 1 : 0;
  }
  if (t >= 32 && t < 64) {
    int e = t - 32;
    *(float4*)(als + e*4) = *(const float4*)(ws + OFF_ALPHA + (size_t)(e0base+e)*4);
  }
  for (int idx = t; idx < 800; idx += 256) D2s[idx] = D2g[(size_t)e0base*25 + idx];
  __syncthreads();
  for (int idx = t; idx < 800; idx += 256) {
    int e = idx/25, q = idx%25, nn = q/5, p = q%5;
    float s = 0.f;
    for (int m = 0; m < 5; ++m) s += D2s[e*25+nn*5+m]*D2s[e*25+p*5+m];
    G2s[idx] = s;
  }
  for (int k = 0; k < 2; ++k) {   // h1 -> msgb[0:2048]
    int q = g + 8*k;
    float4 v = *(const float4*)(ws + OFF_H1 + (size_t)(e0base+lane_e)*64 + 4*q);
    msgb[(4*q+0)*32+lane_e] = v.x; msgb[(4*q+1)*32+lane_e] = v.y;
    msgb[(4*q+2)*32+lane_e] = v.z; msgb[(4*q+3)*32+lane_e] = v.w;
  }
  __syncthreads();
  float rad[4][4];
  {
    int oc6 = r % 6, o0r = 4*oc6;
    float acc[4][4] = {};
    gemm44(acc, ws + OFF_RW2T + 144 + o0r, 168, msgb + e0, 64);
    for (int i = 0; i < 4; ++i) {
      float b = r_b2[144 + o0r + i];
      for (int jj = 0; jj < 4; ++jj) rad[i][jj] = acc[i][jj] + b;
    }
  }
  __syncthreads();
  // raw edge v2 -> ebuf [m][c][e], equiv_ln row 1
  {
    const float* ep = edge_fea + (size_t)(e0base+lane_e)*360 + 240;
    for (int k = 0; k < 4; ++k) {
      int q = g + 8*k;
      if (q < 30) {
        float4 v = *(const float4*)(ep + 4*q);
        float vv[4] = {v.x,v.y,v.z,v.w};
        for (int i = 0; i < 4; ++i) { int f = 4*q+i; ebuf[((f%5)*24 + f/5)*32 + lane_e] = vv[i]; }
      }
    }
  }
  __syncthreads();
  if (t < 32) {
    float ss = 0.f;
    for (int row = 0; row < 120; ++row) { float x = ebuf[row*32+t]; ss += x*x; }
    statB[t] = rsqrtf(ss/24.f + 1e-5f);
  }
  __syncthreads();
  for (int idx = t; idx < 3840; idx += 256) {
    int row = idx >> 5, e = idx & 31;
    ebuf[idx] *= statB[e]*ln_w2[24 + (row % 24)];
  }
  __syncthreads();
  // message GEMMs over m pairs
  for (int mb = 0; mb < 5; mb += 2) {
    for (int dm = 0; dm < 2; ++dm) {
      int m = mb + dm;
      if (m < 5) {
        const float* sp = ws + OFF_NODE_V2 + (size_t)srcs[lane_e]*120 + m*24;
        const float* dp = ws + OFF_NODE_V2 + (size_t)dsts[lane_e]*120 + m*24;
        int q = g;
        if (q < 6) {
          float4 a = *(const float4*)(sp + 4*q);
          float4 b = *(const float4*)(dp + 4*q);
          float av[4] = {a.x,a.y,a.z,a.w}, bv[4] = {b.x,b.y,b.z,b.w};
          for (int i = 0; i < 4; ++i) {
            buf2[dm*1536 + (4*q+i)*32 + lane_e]      = av[i];
            buf2[dm*1536 + (24+4*q+i)*32 + lane_e]   = bv[i];
          }
        }
        {
          int q2 = g + 2;  // cover q 2..7 with g 0..5 — ensure q<6 handled: q2 in [2..9]
          (void)q2;
        }
      }
    }
    __syncthreads();
    {
      int oc = r % 6, dm = r / 6, m = mb + dm;
      if (r < 12 && m < 5) {
        int o0 = 4*oc;
        float acc[4][4] = {};
        gemm44(acc, ws + OFF_PREW2T + o0, 24, buf2 + dm*1536 + e0, 48);
        gemm44(acc, ws + OFF_PREW2T + 48*24 + o0, 24, ebuf + m*768 + e0, 24);
        for (int i = 0; i < 4; ++i)
          for (int jj = 0; jj < 4; ++jj) msgb[m*768 + (o0+i)*32 + e0+jj] = acc[i][jj];
      }
    }
    __syncthreads();
  }
  // rotate in D2
  for (int idx = t; idx < 3840; idx += 256) {
    int e = idx & 31, row = idx >> 5, c = row % 24, nn = row / 24;
    float s = 0.f;
    for (int m = 0; m < 5; ++m) s = fmaf(D2s[e*25+nn*5+m], msgb[m*768 + c*32 + e], s);
    buf2[nn*768 + c*32 + e] = s;
  }
  __syncthreads();
  // so2#1 GEMM (Wl2[0]) * rad -> ebuf   (oc = r%6, nn = r/6, r<30)
  {
    int oc = r % 6, nn = r / 6;
    if (r < 30) {
      int o0 = 4*oc;
      float acc[4][4] = {};
      gemm44(acc, ws + OFF_WL2T + 0*576 + o0, 24, buf2 + nn*768 + e0, 24);
      for (int i = 0; i < 4; ++i)
        for (int jj = 0; jj < 4; ++jj) ebuf[nn*768 + (o0+i)*32 + e0+jj] = acc[i][jj]*rad[i][jj];
    }
  }
  __syncthreads();
  if (t < 32) {
    float ss = 0.f;
    for (int row = 0; row < 120; ++row) { float x = ebuf[row*32+t]; ss += x*x; }
    statB[t] = rsqrtf(ss/24.f + 1e-5f);
  }
  __syncthreads();
  for (int idx = t; idx < 3840; idx += 256) {
    int row = idx >> 5, e = idx & 31;
    ebuf[idx] *= statB[e]*ln_w2[48 + (row % 24)];
  }
  __syncthreads();
  // fused G2 rotation
  for (int idx = t; idx < 3840; idx += 256) {
    int e = idx & 31, row = idx >> 5, c = row % 24, nn = row / 24;
    float s = 0.f;
    for (int p = 0; p < 5; ++p) s = fmaf(G2s[e*25+nn*5+p], ebuf[p*768 + c*32 + e], s);
    buf2[nn*768 + c*32 + e] = s;
  }
  __syncthreads();
  // so2#2 GEMM (Wl2[1]) -> ebuf
  {
    int oc = r % 6, nn = r / 6;
    if (r < 30) {
      int o0 = 4*oc;
      float acc[4][4] = {};
      gemm44(acc, ws + OFF_WL2T + 1*576 + o0, 24, buf2 + nn*768 + e0, 24);
      for (int i = 0; i < 4; ++i)
        for (int jj = 0; jj < 4; ++jj) ebuf[nn*768 + (o0+i)*32 + e0+jj] = acc[i][jj];
    }
  }
  __syncthreads();
  // rotate back D2^T -> buf2
  for (int idx = t; idx < 3840; idx += 256) {
    int e = idx & 31, row = idx >> 5, c = row % 24, nn = row / 24;
    float s = 0.f;
    for (int m = 0; m < 5; ++m) s = fmaf(D2s[e*25+m*5+nn], ebuf[m*768 + c*32 + e], s);
    buf2[nn*768 + c*32 + e] = s;
  }
  __syncthreads();
  // onsite + alpha + scatter
  for (int idx = t; idx < 3840; idx += 256) {
    int e = idx & 31, row = idx >> 5, c = row % 24, nn = row / 24;
    float v;
    if (flags[e]) {
      float s = 0.f;
      for (int cc = 0; cc < 24; ++cc)
        s = fmaf(ws[OFF_WL2T + 2*576 + cc*24 + c], msgb[nn*768 + cc*32 + e], s);
      v = s;
    } else v = buf2[idx];
    v *= als[e*4 + c/6];
    buf2[idx] = v;
    atomicAdd(ws + OFF_NODEMSG + (size_t)dsts[e]*360 + 240 + c*5 + nn, v);
  }
  __syncthreads();
  // restage RAW edge v2 -> ebuf
  {
    const float* ep = edge_fea + (size_t)(e0base+lane_e)*360 + 240;
    for (int k = 0; k < 4; ++k) {
      int q = g + 8*k;
      if (q < 30) {
        float4 v = *(const float4*)(ep + 4*q);
        float vv[4] = {v.x,v.y,v.z,v.w};
        for (int i = 0; i < 4; ++i) { int f = 4*q+i; ebuf[((f%5)*24 + f/5)*32 + lane_e] = vv[i]; }
      }
    }
  }
  __syncthreads();
  // edge_out: Wl2[4]@scaled + Wl2[6]@raw -> msgb flat [5o+n][e]
  {
    int oc = r % 6, nn = r / 6;
    if (r < 30) {
      int o0 = 4*oc;
      float acc[4][4] = {};
      gemm44(acc, ws + OFF_WL2T + 4*576 + o0, 24, buf2 + nn*768 + e0, 24);
      gemm44(acc, ws + OFF_WL2T + 6*576 + o0, 24, ebuf + nn*768 + e0, 24);
      for (int i = 0; i < 4; ++i)
        for (int jj = 0; jj < 4; ++jj) msgb[(5*(o0+i)+nn)*32 + e0+jj] = acc[i][jj];
    }
  }
  __syncthreads();
  {
    float* op = out + (size_t)N_NODES*360 + (size_t)(e0base+lane_e)*360 + 240;
    for (int k = 0; k < 4; ++k) {
      int q = g + 8*k;
      if (q < 30) {
        float4 v = { msgb[(4*q+0)*32+lane_e], msgb[(4*q+1)*32+lane_e],
                     msgb[(4*q+2)*32+lane_e], msgb[(4*q+3)*32+lane_e] };
        *(float4*)(op + 4*q) = v;
      }
    }
  }
}

// ---------------- node output ----------------
__global__ __launch_bounds__(256) void k_nodeout(
    const float* __restrict__ node_fea, float* ws, float* out)
{
  __shared__ __align__(16) float bufA[3*48*32];
  __shared__ __align__(16) float bufB[3*48*32];
  __shared__ __align__(16) float obuf[3*48*32];
  const int t = threadIdx.x, lane_e = t & 31, g = t >> 5;
  const int n0 = blockIdx.x * 32;
  const int n = n0 + lane_e;
  const bool valid = n < N_NODES;
  const int eq = t & 7, oc = t >> 3, r = t >> 3, e0 = 4*eq, o0 = 4*oc;

  // ---- scalars
  for (int k = 0; k < 3; ++k) {
    int q = g + 8*k;
    float4 a = valid ? *(const float4*)(ws + OFF_NODEMSG + (size_t)n*360 + 4*q) : make_float4(0,0,0,0);
    float4 b = valid ? *(const float4*)(node_fea + (size_t)n*360 + 4*q) : make_float4(0,0,0,0);
    float av[4] = {a.x,a.y,a.z,a.w}, bv[4] = {b.x,b.y,b.z,b.w};
    for (int i = 0; i < 4; ++i) {
      bufA[(4*q+i)*32 + lane_e] = av[i];
      bufB[(4*q+i)*32 + lane_e] = bv[i];
    }
  }
  __syncthreads();
  if (oc < 24) {
    float acc[4][4] = {};
    gemm44(acc, ws + OFF_WL0T + 3*9216 + o0, 96, bufA + e0, 96);
    gemm44(acc, ws + OFF_WL0T + 5*9216 + o0, 96, bufB + e0, 96);
    for (int jj = 0; jj < 4; ++jj) {
      int n2 = n0 + e0 + jj;
      if (n2 < N_NODES) {
        float4 v = { acc[0][jj], acc[1][jj], acc[2][jj], acc[3][jj] };
        *(float4*)(out + (size_t)n2*360 + o0) = v;
      }
    }
  }
  __syncthreads();
  // ---- v1
  for (int k = 0; k < 5; ++k) {
    int q = g + 8*k;
    if (q < 36) {
      float4 a = valid ? *(const float4*)(ws + OFF_NODEMSG + (size_t)n*360 + 96 + 4*q) : make_float4(0,0,0,0);
      float4 b = valid ? *(const float4*)(node_fea + (size_t)n*360 + 96 + 4*q) : make_float4(0,0,0,0);
      float av[4] = {a.x,a.y,a.z,a.w}, bv[4] = {b.x,b.y,b.z,b.w};
      for (int i = 0; i < 4; ++i) {
        int f = 4*q+i; int row = (f%3)*48 + f/3;
        bufA[row*32 + lane_e] = av[i];
        bufB[row*32 + lane_e] = bv[i];
      }
    }
  }
  __syncthreads();
  for (int nb = 0; nb < 3; nb += 2) {
    int oc12 = r % 12, dn = r / 12, nn = nb + dn;
    if (r < 24 && nn < 3) {
      int oo = 4*oc12;
      float acc[4][4] = {};
      gemm44(acc, ws + OFF_WL1T + 3*2304 + oo, 48, bufA + nn*1536 + e0, 48);
      gemm44(acc, ws + OFF_WL1T + 5*2304 + oo, 48, bufB + nn*1536 + e0, 48);
      for (int i = 0; i < 4; ++i)
        for (int jj = 0; jj < 4; ++jj) obuf[(3*(oo+i)+nn)*32 + e0+jj] = acc[i][jj];
    }
  }
  __syncthreads();
  for (int k = 0; k < 5; ++k) {
    int q = g + 8*k;
    if (q < 36 && valid) {
      float4 v = { obuf[(4*q+0)*32+lane_e], obuf[(4*q+1)*32+lane_e],
                   obuf[(4*q+2)*32+lane_e], obuf[(4*q+3)*32+lane_e] };
      *(float4*)(out + (size_t)n*360 + 96 + 4*q) = v;
    }
  }
  __syncthreads();
  // ---- v2
  for (int k = 0; k < 4; ++k) {
    int q = g + 8*k;
    if (q < 30) {
      float4 a = valid ? *(const float4*)(ws + OFF_NODEMSG + (size_t)n*360 + 240 + 4*q) : make_float4(0,0,0,0);
      float4 b = valid ? *(const float4*)(node_fea + (size_t)n*360 + 240 + 4*q) : make_float4(0,0,0,0);
      float av[4] = {a.x,a.y,a.z,a.w}, bv[4] = {b.x,b.y,b.z,b.w};
      for (int i = 0; i < 4; ++i) {
        int f = 4*q+i; int row = (f%5)*24 + f/5;
        bufA[row*32 + lane_e] = av[i];
        bufB[row*32 + lane_e] = bv[i];
      }
    }
  }
  __syncthreads();
  {
    int oc6 = r % 6, nn = r / 6;
    if (r < 30) {
      int oo = 4*oc6;
      float acc[4][4] = {};
      gemm44(acc, ws + OFF_WL2T + 3*576 + oo, 24, bufA + nn*768 + e0, 24);
      gemm44(acc, ws + OFF_WL2T + 5*576 + oo, 24, bufB + nn*768 + e0, 24);
      for (int i = 0; i < 4; ++i)
        for (int jj = 0; jj < 4; ++jj) obuf[(5*(oo+i)+nn)*32 + e0+jj] = acc[i][jj];
    }
  }
  __syncthreads();
  for (int k = 0; k < 4; ++k) {
    int q = g + 8*k;
    if (q < 30 && valid) {
      float4 v = { obuf[(4*q+0)*32+lane_e], obuf[(4*q+1)*32+lane_e],
                   obuf[(4*q+2)*32+lane_e], obuf[(4*q+3)*32+lane_e] };
      *(float4*)(out + (size_t)n*360 + 240 + 4*q) = v;
    }
  }
}

extern "C" void kernel_launch(void* const* d_in, const int* in_sizes, int n_in,
                              void* d_out, int out_size, void* d_ws, size_t ws_size,
                              hipStream_t stream) {
  (void)in_sizes; (void)n_in; (void)out_size; (void)ws_size;
  const float* node_fea = (const float*)d_in[0];
  const float* edge_fea = (const float*)d_in[1];
  const float* ele      = (const float*)d_in[3];
  const float* edge_vec = (const float*)d_in[4];
  const float* D1       = (const float*)d_in[5];
  const float* D2       = (const float*)d_in[6];
  const float* Wl0      = (const float*)d_in[7];
  const float* Wl1      = (const float*)d_in[8];
  const float* Wl2      = (const float*)d_in[9];
  const float* preW0    = (const float*)d_in[10];
  const float* preW1    = (const float*)d_in[11];
  const float* preW2    = (const float*)d_in[12];
  const float* ln_w0    = (const float*)d_in[13];
  const float* ln_b0    = (const float*)d_in[14];
  const float* ln_w1    = (const float*)d_in[15];
  const float* ln_w2    = (const float*)d_in[16];
  const float* qk_W1    = (const float*)d_in[17];
  const float* qk_b1    = (const float*)d_in[18];
  const float* qk_lnw   = (const float*)d_in[19];
  const float* qk_lnb   = (const float*)d_in[20];
  const float* qk_W2    = (const float*)d_in[21];
  const float* qk_b2    = (const float*)d_in[22];
  const float* a_W1     = (const float*)d_in[23];
  const float* a_b1     = (const float*)d_in[24];
  const float* a_ln1w   = (const float*)d_in[25];
  const float* a_ln1b   = (const float*)d_in[26];
  const float* a_W2     = (const float*)d_in[27];
  const float* a_b2     = (const float*)d_in[28];
  const float* a_ln2w   = (const float*)d_in[29];
  const float* a_ln2b   = (const float*)d_in[30];
  const float* a_W3     = (const float*)d_in[31];
  const float* a_b3     = (const float*)d_in[32];
  const float* r_W1     = (const float*)d_in[33];
  const float* r_b1     = (const float*)d_in[34];
  const float* r_W2     = (const float*)d_in[35];
  const float* r_b2     = (const float*)d_in[36];
  const int* edge_src   = (const int*)d_in[37];
  const int* edge_dst   = (const int*)d_in[38];
  float* ws  = (float*)d_ws;
  float* out = (float*)d_out;

  k_prep<<<dim3(33), dim3(256), 0, stream>>>(preW0, preW1, preW2, Wl0, Wl1, Wl2,
                                             qk_W1, qk_W2, a_W1, a_W2, a_W3, r_W1, r_W2, ws);
  hipMemsetAsync((char*)d_ws + (size_t)OFF_NODEMSG*sizeof(float), 0,
                 (size_t)N_NODES*360*sizeof(float), stream);
  k_node<<<dim3((N_NODES+31)/32), dim3(256), 0, stream>>>(node_fea, ln_w0, ln_b0, ln_w1, ln_w2,
                                                          qk_b1, qk_lnw, qk_lnb, qk_b2, ws);
  k_alpha<<<dim3(N_EDGES/32), dim3(256), 0, stream>>>(ele, r_b1, a_b1, a_ln1w, a_ln1b,
                                                      a_b2, a_ln2w, a_ln2b, a_b3,
                                                      edge_src, edge_dst, ws);
  k_sc<<<dim3(N_EDGES/32), dim3(256), 0, stream>>>(edge_fea, edge_vec, ln_w0, ln_b0, r_b2,
                                                   edge_src, edge_dst, ws, out);
  k_v1c<<<dim3(N_EDGES/32), dim3(256), 0, stream>>>(edge_fea, edge_vec, D1, ln_w1, r_b2,
                                                    edge_src, edge_dst, ws, out);
  k_v2c<<<dim3(N_EDGES/32), dim3(256), 0, stream>>>(edge_fea, edge_vec, D2, ln_w2, r_b2,
                                                    edge_src, edge_dst, ws, out);
  k_nodeout<<<dim3((N_NODES+31)/32), dim3(256), 0, stream>>>(node_fea, ws, out);
}

// Round 2
// 2473.890 us; speedup vs baseline: 1.8632x; 1.8632x over previous
//
#include <hip/hip_runtime.h>
#include <math.h>

#define N_NODES 10000
#define N_EDGES 160000

// ---------------- workspace offsets (floats) ----------------
#define OFF_PREW0T   0u          // [288][96]
#define OFF_PREW1T   27648u      // [144][48]
#define OFF_PREW2T   34560u      // [72][24]
#define OFF_WL0T     36288u      // 7 x [96][96]
#define OFF_WL1T     100800u     // 7 x [48][48]
#define OFF_WL2T     116928u     // 7 x [24][24]
#define OFF_QKW1T    120960u     // 2 x [96][64]
#define OFF_QKW2T    133248u     // 2 x [64][64]
#define OFF_AW1T     141440u     // [64][64]
#define OFF_AW2T     145536u     // [64][64]
#define OFF_AW3T     149632u     // [64][4]
#define OFF_RW1T     149888u     // [64][64]
#define OFF_RW2T     153984u     // [64][168]
#define OFF_NODE_S   164736u     // [N][96]
#define OFF_NODE_V1  1124736u    // [N][3][48]
#define OFF_NODE_V2  2564736u    // [N][5][24]
#define OFF_QNODE    3764736u    // [N][64]
#define OFF_KNODE    4404736u    // [N][64]
#define OFF_ALPHA    5044736u    // [E][4]
#define OFF_H1       5684736u    // [E][64]
#define OFF_NODEMSG  15924736u   // [N][360] gather result
// CSR (int views)
#define OFFI_DEG     19524736u   // [N]
#define OFFI_CUR     19534736u   // [N]
#define OFFI_OFFS    19544736u   // [N+1]
#define OFFI_EIDX    19554737u   // [E]
// total ~78.9 MB

__device__ __forceinline__ float siluf(float x) { return x / (1.f + expf(-x)); }

__device__ __forceinline__ void gemm44(float (&acc)[4][4],
    const float* __restrict__ w, const int O,
    const float* __restrict__ x, const int C)
{
  for (int c = 0; c < C; ++c) {
    const float4 wv = *reinterpret_cast<const float4*>(w + (size_t)c * (size_t)O);
    const float4 xv = *reinterpret_cast<const float4*>(x + (c << 5));
    acc[0][0] = fmaf(wv.x, xv.x, acc[0][0]); acc[0][1] = fmaf(wv.x, xv.y, acc[0][1]);
    acc[0][2] = fmaf(wv.x, xv.z, acc[0][2]); acc[0][3] = fmaf(wv.x, xv.w, acc[0][3]);
    acc[1][0] = fmaf(wv.y, xv.x, acc[1][0]); acc[1][1] = fmaf(wv.y, xv.y, acc[1][1]);
    acc[1][2] = fmaf(wv.y, xv.z, acc[1][2]); acc[1][3] = fmaf(wv.y, xv.w, acc[1][3]);
    acc[2][0] = fmaf(wv.z, xv.x, acc[2][0]); acc[2][1] = fmaf(wv.z, xv.y, acc[2][1]);
    acc[2][2] = fmaf(wv.z, xv.z, acc[2][2]); acc[2][3] = fmaf(wv.z, xv.w, acc[2][3]);
    acc[3][0] = fmaf(wv.w, xv.x, acc[3][0]); acc[3][1] = fmaf(wv.w, xv.y, acc[3][1]);
    acc[3][2] = fmaf(wv.w, xv.z, acc[3][2]); acc[3][3] = fmaf(wv.w, xv.w, acc[3][3]);
  }
}

__device__ __forceinline__ void gemm24(float (&acc)[2][4],
    const float* __restrict__ w, const int O,
    const float* __restrict__ x, const int C)
{
  for (int c = 0; c < C; ++c) {
    const float2 wv = *reinterpret_cast<const float2*>(w + (size_t)c * (size_t)O);
    const float4 xv = *reinterpret_cast<const float4*>(x + (c << 5));
    acc[0][0] = fmaf(wv.x, xv.x, acc[0][0]); acc[0][1] = fmaf(wv.x, xv.y, acc[0][1]);
    acc[0][2] = fmaf(wv.x, xv.z, acc[0][2]); acc[0][3] = fmaf(wv.x, xv.w, acc[0][3]);
    acc[1][0] = fmaf(wv.y, xv.x, acc[1][0]); acc[1][1] = fmaf(wv.y, xv.y, acc[1][1]);
    acc[1][2] = fmaf(wv.y, xv.z, acc[1][2]); acc[1][3] = fmaf(wv.y, xv.w, acc[1][3]);
  }
}

// parallel LN stats: mean + rsqrt(var) over R rows of buf[R][32]
__device__ __forceinline__ void ln_stats(const float* buf, int R, float* pbuf,
                                         float* statA, float* statB, int t,
                                         float eps, float invR)
{
  int e = t & 31, slab = t >> 5;
  float s = 0.f, q = 0.f;
  for (int r = slab; r < R; r += 8) { float x = buf[r*32+e]; s += x; q = fmaf(x,x,q); }
  pbuf[slab*32+e] = s; pbuf[256 + slab*32+e] = q;
  __syncthreads();
  if (t < 32) {
    float ss = 0.f, qq = 0.f;
    for (int k = 0; k < 8; ++k) { ss += pbuf[k*32+t]; qq += pbuf[256+k*32+t]; }
    float mu = ss * invR;
    statA[t] = mu;
    statB[t] = rsqrtf(fmaxf(qq*invR - mu*mu, 0.f) + eps);
  }
  __syncthreads();
}

// parallel vec stats: rsqrt(sumsq/C + eps) over R rows
__device__ __forceinline__ void vec_stats(const float* buf, int R, float* pbuf,
                                          float* statB, int t, float eps, float invC)
{
  int e = t & 31, slab = t >> 5;
  float q = 0.f;
  for (int r = slab; r < R; r += 8) { float x = buf[r*32+e]; q = fmaf(x,x,q); }
  pbuf[slab*32+e] = q;
  __syncthreads();
  if (t < 32) {
    float qq = 0.f;
    for (int k = 0; k < 8; ++k) qq += pbuf[k*32+t];
    statB[t] = rsqrtf(qq*invC + eps);
  }
  __syncthreads();
}

// ---------------- weight transposes ----------------
__global__ __launch_bounds__(256) void k_prep(
    const float* preW0, const float* preW1, const float* preW2,
    const float* Wl0, const float* Wl1, const float* Wl2,
    const float* qkW1, const float* qkW2,
    const float* aW1, const float* aW2, const float* aW3,
    const float* rW1, const float* rW2, float* ws)
{
  int j = blockIdx.x;
  const float* src; float* dst; int O, C;
  if (j == 0)      { src = preW0; dst = ws + OFF_PREW0T; O = 96;  C = 288; }
  else if (j == 1) { src = preW1; dst = ws + OFF_PREW1T; O = 48;  C = 144; }
  else if (j == 2) { src = preW2; dst = ws + OFF_PREW2T; O = 24;  C = 72;  }
  else if (j < 10) { int k = j-3;  src = Wl0 + k*9216; dst = ws + OFF_WL0T + k*9216; O = 96; C = 96; }
  else if (j < 17) { int k = j-10; src = Wl1 + k*2304; dst = ws + OFF_WL1T + k*2304; O = 48; C = 48; }
  else if (j < 24) { int k = j-17; src = Wl2 + k*576;  dst = ws + OFF_WL2T + k*576;  O = 24; C = 24; }
  else if (j < 26) { int k = j-24; src = qkW1 + k*6144; dst = ws + OFF_QKW1T + k*6144; O = 64; C = 96; }
  else if (j < 28) { int k = j-26; src = qkW2 + k*4096; dst = ws + OFF_QKW2T + k*4096; O = 64; C = 64; }
  else if (j == 28){ src = aW1; dst = ws + OFF_AW1T; O = 64; C = 64; }
  else if (j == 29){ src = aW2; dst = ws + OFF_AW2T; O = 64; C = 64; }
  else if (j == 30){ src = aW3; dst = ws + OFF_AW3T; O = 4;  C = 64; }
  else if (j == 31){ src = rW1; dst = ws + OFF_RW1T; O = 64; C = 64; }
  else             { src = rW2; dst = ws + OFF_RW2T; O = 168; C = 64; }
  int tot = O * C;
  for (int idx = threadIdx.x; idx < tot; idx += 256) {
    int o = idx / C, c = idx % C;
    dst[c*O + o] = src[idx];
  }
}

// ---------------- CSR build ----------------
__global__ __launch_bounds__(256) void k_hist(const int* __restrict__ edge_dst, int* deg) {
  int e = blockIdx.x * 256 + threadIdx.x;
  if (e < N_EDGES) atomicAdd(&deg[edge_dst[e]], 1);
}

__global__ __launch_bounds__(256) void k_scan(const int* __restrict__ deg, int* offs) {
  __shared__ int ps[256];
  const int t = threadIdx.x;
  const int PER = 40;
  int base = t * PER;
  int s = 0;
  for (int i = 0; i < PER; ++i) { int j = base + i; if (j < N_NODES) s += deg[j]; }
  ps[t] = s;
  __syncthreads();
  for (int d = 1; d < 256; d <<= 1) {
    int v = (t >= d) ? ps[t-d] : 0;
    __syncthreads();
    ps[t] += v;
    __syncthreads();
  }
  int run = (t ? ps[t-1] : 0);
  for (int i = 0; i < PER; ++i) {
    int j = base + i;
    if (j < N_NODES) { offs[j] = run; run += deg[j]; }
  }
  if (t == 255) offs[N_NODES] = run;
}

__global__ __launch_bounds__(256) void k_scatter(const int* __restrict__ edge_dst,
                                                 const int* __restrict__ offs,
                                                 int* cur, int* eidx) {
  int e = blockIdx.x * 256 + threadIdx.x;
  if (e < N_EDGES) {
    int d = edge_dst[e];
    int p = atomicAdd(&cur[d], 1);
    eidx[offs[d] + p] = e;
  }
}

// ---------------- node kernel: equiv_ln + q/k mlp2 ----------------
__global__ __launch_bounds__(256) void k_node(
    const float* __restrict__ node_fea,
    const float* __restrict__ ln_w0, const float* __restrict__ ln_b0,
    const float* __restrict__ ln_w1, const float* __restrict__ ln_w2,
    const float* __restrict__ qk_b1, const float* __restrict__ qk_lnw,
    const float* __restrict__ qk_lnb, const float* __restrict__ qk_b2,
    float* __restrict__ ws)
{
  __shared__ __align__(16) float sbuf[96*32];
  __shared__ __align__(16) float vbuf[3*48*32];
  __shared__ __align__(16) float pbuf[512];
  __shared__ float statA[32], statB[32];
  const int t = threadIdx.x;
  const int lane_e = t & 31, g = t >> 5;
  const int n0 = blockIdx.x * 32;
  const int n = n0 + lane_e;
  const bool valid = n < N_NODES;
  const int eq = t & 7, oc = t >> 3, e0 = 4*eq, o0 = 4*oc;

  for (int k = 0; k < 3; ++k) {
    int q = g + 8*k;
    float4 v = valid ? *(const float4*)(node_fea + (size_t)n*360 + 4*q)
                     : make_float4(0.f,0.f,0.f,0.f);
    sbuf[(4*q+0)*32+lane_e] = v.x; sbuf[(4*q+1)*32+lane_e] = v.y;
    sbuf[(4*q+2)*32+lane_e] = v.z; sbuf[(4*q+3)*32+lane_e] = v.w;
  }
  __syncthreads();
  ln_stats(sbuf, 96, pbuf, statA, statB, t, 1e-5f, 1.f/96.f);
  for (int idx = t; idx < 96*32; idx += 256) {
    int c = idx >> 5, e = idx & 31;
    sbuf[idx] = (sbuf[idx]-statA[e])*statB[e]*ln_w0[c] + ln_b0[c];
  }
  __syncthreads();
  for (int k = 0; k < 3; ++k) {
    int q = g + 8*k;
    if (valid) {
      float4 v = { sbuf[(4*q+0)*32+lane_e], sbuf[(4*q+1)*32+lane_e],
                   sbuf[(4*q+2)*32+lane_e], sbuf[(4*q+3)*32+lane_e] };
      *(float4*)(ws + OFF_NODE_S + (size_t)n*96 + 4*q) = v;
    }
  }
  for (int p = 0; p < 2; ++p) {
    if (oc < 16) {
      float acc[4][4] = {};
      gemm44(acc, ws + OFF_QKW1T + p*6144 + o0, 64, sbuf + e0, 96);
      for (int i = 0; i < 4; ++i) {
        float b = qk_b1[p*64 + o0 + i];
        float4 v = { acc[i][0]+b, acc[i][1]+b, acc[i][2]+b, acc[i][3]+b };
        *(float4*)(vbuf + (o0+i)*32 + e0) = v;
      }
    }
    __syncthreads();
    ln_stats(vbuf, 64, pbuf, statA, statB, t, 1e-6f, 1.f/64.f);
    for (int idx = t; idx < 64*32; idx += 256) {
      int c = idx >> 5, e = idx & 31;
      float x = (vbuf[idx]-statA[e])*statB[e]*qk_lnw[p*64+c] + qk_lnb[p*64+c];
      vbuf[idx] = siluf(x);
    }
    __syncthreads();
    if (oc < 16) {
      float acc[4][4] = {};
      gemm44(acc, ws + OFF_QKW2T + p*4096 + o0, 64, vbuf + e0, 64);
      size_t base = (p == 0) ? OFF_QNODE : OFF_KNODE;
      for (int jj = 0; jj < 4; ++jj) {
        int n2 = n0 + e0 + jj;
        if (n2 < N_NODES) {
          float4 v = { acc[0][jj]+qk_b2[p*64+o0+0], acc[1][jj]+qk_b2[p*64+o0+1],
                       acc[2][jj]+qk_b2[p*64+o0+2], acc[3][jj]+qk_b2[p*64+o0+3] };
          *(float4*)(ws + base + (size_t)n2*64 + o0) = v;
        }
      }
    }
    __syncthreads();
  }
  // v1
  for (int k = 0; k < 5; ++k) {
    int q = g + 8*k;
    if (q < 36) {
      float4 v = valid ? *(const float4*)(node_fea + (size_t)n*360 + 96 + 4*q)
                       : make_float4(0.f,0.f,0.f,0.f);
      float vv[4] = {v.x, v.y, v.z, v.w};
      for (int i = 0; i < 4; ++i) {
        int f = 4*q+i; vbuf[((f%3)*48 + f/3)*32 + lane_e] = vv[i];
      }
    }
  }
  __syncthreads();
  vec_stats(vbuf, 144, pbuf, statB, t, 1e-5f, 1.f/48.f);
  for (int idx = t; idx < 144*32; idx += 256) {
    int row = idx >> 5, e = idx & 31;
    vbuf[idx] *= statB[e]*ln_w1[row % 48];
  }
  __syncthreads();
  for (int k = 0; k < 5; ++k) {
    int q = g + 8*k;
    if (q < 36 && valid) {
      float4 v = { vbuf[(4*q+0)*32+lane_e], vbuf[(4*q+1)*32+lane_e],
                   vbuf[(4*q+2)*32+lane_e], vbuf[(4*q+3)*32+lane_e] };
      *(float4*)(ws + OFF_NODE_V1 + (size_t)n*144 + 4*q) = v;
    }
  }
  __syncthreads();
  // v2
  for (int k = 0; k < 4; ++k) {
    int q = g + 8*k;
    if (q < 30) {
      float4 v = valid ? *(const float4*)(node_fea + (size_t)n*360 + 240 + 4*q)
                       : make_float4(0.f,0.f,0.f,0.f);
      float vv[4] = {v.x, v.y, v.z, v.w};
      for (int i = 0; i < 4; ++i) {
        int f = 4*q+i; vbuf[((f%5)*24 + f/5)*32 + lane_e] = vv[i];
      }
    }
  }
  __syncthreads();
  vec_stats(vbuf, 120, pbuf, statB, t, 1e-5f, 1.f/24.f);
  for (int idx = t; idx < 120*32; idx += 256) {
    int row = idx >> 5, e = idx & 31;
    vbuf[idx] *= statB[e]*ln_w2[row % 24];
  }
  __syncthreads();
  for (int k = 0; k < 4; ++k) {
    int q = g + 8*k;
    if (q < 30 && valid) {
      float4 v = { vbuf[(4*q+0)*32+lane_e], vbuf[(4*q+1)*32+lane_e],
                   vbuf[(4*q+2)*32+lane_e], vbuf[(4*q+3)*32+lane_e] };
      *(float4*)(ws + OFF_NODE_V2 + (size_t)n*120 + 4*q) = v;
    }
  }
}

// ---------------- per-edge: alpha + h1 ----------------
__global__ __launch_bounds__(256) void k_alpha(
    const float* __restrict__ ele, const float* __restrict__ r_b1,
    const float* __restrict__ a_b1, const float* __restrict__ a_ln1w, const float* __restrict__ a_ln1b,
    const float* __restrict__ a_b2, const float* __restrict__ a_ln2w, const float* __restrict__ a_ln2b,
    const float* __restrict__ a_b3,
    const int* __restrict__ edge_src, const int* __restrict__ edge_dst,
    float* __restrict__ ws)
{
  __shared__ __align__(16) float eb[64*32];
  __shared__ __align__(16) float hb[64*32];
  __shared__ __align__(16) float pbuf[512];
  __shared__ float statA[32], statB[32];
  __shared__ int srcs[32], dsts[32];
  const int t = threadIdx.x, lane_e = t & 31, g = t >> 5;
  const int e0base = blockIdx.x * 32;
  const int eq = t & 7, oc = t >> 3, e0 = 4*eq, o0 = 4*oc;
  if (t < 32) { srcs[t] = edge_src[e0base+t]; dsts[t] = edge_dst[e0base+t]; }
  for (int k = 0; k < 2; ++k) {
    int q = g + 8*k;
    float4 v = *(const float4*)(ele + (size_t)(e0base+lane_e)*64 + 4*q);
    eb[(4*q+0)*32+lane_e] = v.x; eb[(4*q+1)*32+lane_e] = v.y;
    eb[(4*q+2)*32+lane_e] = v.z; eb[(4*q+3)*32+lane_e] = v.w;
  }
  __syncthreads();
  if (oc < 16) {
    float acc[4][4] = {};
    gemm44(acc, ws + OFF_RW1T + o0, 64, eb + e0, 64);
    for (int jj = 0; jj < 4; ++jj) {
      float4 v = { siluf(acc[0][jj]+r_b1[o0+0]), siluf(acc[1][jj]+r_b1[o0+1]),
                   siluf(acc[2][jj]+r_b1[o0+2]), siluf(acc[3][jj]+r_b1[o0+3]) };
      *(float4*)(ws + OFF_H1 + (size_t)(e0base+e0+jj)*64 + o0) = v;
    }
    float acc2[4][4] = {};
    gemm44(acc2, ws + OFF_AW1T + o0, 64, eb + e0, 64);
    for (int i = 0; i < 4; ++i) {
      float b = a_b1[o0+i];
      float4 v = { acc2[i][0]+b, acc2[i][1]+b, acc2[i][2]+b, acc2[i][3]+b };
      *(float4*)(hb + (o0+i)*32 + e0) = v;
    }
  }
  __syncthreads();
  ln_stats(hb, 64, pbuf, statA, statB, t, 1e-6f, 1.f/64.f);
  for (int idx = t; idx < 64*32; idx += 256) {
    int c = idx >> 5, e = idx & 31;
    hb[idx] = siluf((hb[idx]-statA[e])*statB[e]*a_ln1w[c] + a_ln1b[c]);
  }
  __syncthreads();
  if (oc < 16) {
    float acc[4][4] = {};
    gemm44(acc, ws + OFF_AW2T + o0, 64, hb + e0, 64);
    for (int i = 0; i < 4; ++i) {
      float b = a_b2[o0+i];
      float4 v = { acc[i][0]+b, acc[i][1]+b, acc[i][2]+b, acc[i][3]+b };
      *(float4*)(eb + (o0+i)*32 + e0) = v;
    }
  }
  __syncthreads();
  ln_stats(eb, 64, pbuf, statA, statB, t, 1e-6f, 1.f/64.f);
  for (int idx = t; idx < 64*32; idx += 256) {
    int c = idx >> 5, e = idx & 31;
    eb[idx] = siluf((eb[idx]-statA[e])*statB[e]*a_ln2w[c] + a_ln2b[c]);
  }
  __syncthreads();
  if (t < 128) {
    int e = t & 31, j = t >> 5;
    float h3 = a_b3[j];
    for (int c = 0; c < 64; ++c)
      h3 = fmaf(eb[c*32+e], ws[OFF_AW3T + c*4+j], h3);
    const float* qp = ws + OFF_QNODE + (size_t)dsts[e]*64 + 16*j;
    const float* kp = ws + OFF_KNODE + (size_t)srcs[e]*64 + 16*j;
    float qk = 0.f;
    for (int u = 0; u < 4; ++u) {
      float4 qv = *(const float4*)(qp + 4*u);
      float4 kv = *(const float4*)(kp + 4*u);
      qk += qv.x*kv.x + qv.y*kv.y + qv.z*kv.z + qv.w*kv.w;
    }
    ws[OFF_ALPHA + (size_t)(e0base+e)*4 + j] = qk*0.25f + h3;
  }
}

// ---------------- scalar chain ----------------
__global__ __launch_bounds__(256,3) void k_sc(
    const float* __restrict__ edge_fea, const float* __restrict__ edge_vec,
    const float* __restrict__ ln_w0, const float* __restrict__ ln_b0,
    const float* __restrict__ r_b2,
    const int* __restrict__ edge_src, const int* __restrict__ edge_dst,
    const float* __restrict__ ws, float* __restrict__ emsg)
{
  __shared__ __align__(16) float bA[96*32];
  __shared__ __align__(16) float bB[96*32];
  __shared__ __align__(16) float bC[96*32];   // staging + pbuf
  __shared__ __align__(16) float radb[96*32];
  __shared__ __align__(16) float als[128];
  __shared__ float statA[32], statB[32];
  __shared__ int srcs[32], dsts[32], flags[32];
  const int t = threadIdx.x, lane_e = t & 31, g = t >> 5;
  const int e0base = blockIdx.x * 32;
  const int eq = t & 7, r = t >> 3, e0 = 4*eq;

  if (t < 32) {
    srcs[t] = edge_src[e0base+t]; dsts[t] = edge_dst[e0base+t];
    float vx = edge_vec[(e0base+t)*3+0], vy = edge_vec[(e0base+t)*3+1], vz = edge_vec[(e0base+t)*3+2];
    flags[t] = (vx*vx + vy*vy + vz*vz) < 1e-20f ? 1 : 0;
  }
  if (t >= 32 && t < 64) {
    int e = t - 32;
    *(float4*)(als + e*4) = *(const float4*)(ws + OFF_ALPHA + (size_t)(e0base+e)*4);
  }
  // h1 -> bA (rows 0..63)
  for (int k = 0; k < 2; ++k) {
    int q = g + 8*k;
    float4 v = *(const float4*)(ws + OFF_H1 + (size_t)(e0base+lane_e)*64 + 4*q);
    bA[(4*q+0)*32+lane_e] = v.x; bA[(4*q+1)*32+lane_e] = v.y;
    bA[(4*q+2)*32+lane_e] = v.z; bA[(4*q+3)*32+lane_e] = v.w;
  }
  __syncthreads();
  // radial (s part: 96 outs) -> radb
  if (r < 24) {
    int o0 = 4*r;
    float acc[4][4] = {};
    gemm44(acc, ws + OFF_RW2T + o0, 168, bA + e0, 64);
    for (int i = 0; i < 4; ++i) {
      float b = r_b2[o0+i];
      float4 v = { acc[i][0]+b, acc[i][1]+b, acc[i][2]+b, acc[i][3]+b };
      *(float4*)(radb + (o0+i)*32 + e0) = v;
    }
  }
  __syncthreads();
  // raw edge scalars -> bB, LN (row1 params)
  {
    const float* ep = edge_fea + (size_t)(e0base+lane_e)*360;
    for (int k = 0; k < 3; ++k) {
      int q = g + 8*k;
      float4 c = *(const float4*)(ep + 4*q);
      bB[(4*q+0)*32+lane_e] = c.x; bB[(4*q+1)*32+lane_e] = c.y;
      bB[(4*q+2)*32+lane_e] = c.z; bB[(4*q+3)*32+lane_e] = c.w;
    }
  }
  __syncthreads();
  ln_stats(bB, 96, bC, statA, statB, t, 1e-5f, 1.f/96.f);
  for (int idx = t; idx < 96*32; idx += 256) {
    int c = idx >> 5, e = idx & 31;
    bB[idx] = (bB[idx]-statA[e])*statB[e]*ln_w0[96+c] + ln_b0[96+c];
  }
  __syncthreads();
  // message GEMM: three phases, acc kept in registers
  float mac[4][4] = {};
  const int o0 = 4*r;
  // phase 1: src
  {
    const float* sp = ws + OFF_NODE_S + (size_t)srcs[lane_e]*96;
    for (int k = 0; k < 3; ++k) {
      int q = g + 8*k;
      float4 a = *(const float4*)(sp + 4*q);
      bC[(4*q+0)*32+lane_e] = a.x; bC[(4*q+1)*32+lane_e] = a.y;
      bC[(4*q+2)*32+lane_e] = a.z; bC[(4*q+3)*32+lane_e] = a.w;
    }
  }
  __syncthreads();
  if (r < 24) gemm44(mac, ws + OFF_PREW0T + o0, 96, bC + e0, 96);
  __syncthreads();
  // phase 2: dst
  {
    const float* dp = ws + OFF_NODE_S + (size_t)dsts[lane_e]*96;
    for (int k = 0; k < 3; ++k) {
      int q = g + 8*k;
      float4 a = *(const float4*)(dp + 4*q);
      bC[(4*q+0)*32+lane_e] = a.x; bC[(4*q+1)*32+lane_e] = a.y;
      bC[(4*q+2)*32+lane_e] = a.z; bC[(4*q+3)*32+lane_e] = a.w;
    }
  }
  __syncthreads();
  if (r < 24) {
    gemm44(mac, ws + OFF_PREW0T + 96*96 + o0, 96, bC + e0, 96);
    gemm44(mac, ws + OFF_PREW0T + 192*96 + o0, 96, bB + e0, 96);
    for (int i = 0; i < 4; ++i)
      *(float4*)(bA + (o0+i)*32 + e0) = make_float4(mac[i][0], mac[i][1], mac[i][2], mac[i][3]);
  }
  // onsite (rare)
  {
    int f = flags[t & 31];
    int any = __syncthreads_or(f);   // also serves as barrier after message writeback
    if (any) {
      for (int idx = t; idx < 96*32; idx += 256) {
        int o = idx >> 5, e = idx & 31;
        if (flags[e]) {
          float s = 0.f;
          #pragma unroll 1
          for (int c = 0; c < 96; ++c)
            s = fmaf(ws[OFF_WL0T + 2*9216 + c*96 + o], bA[c*32+e], s);
          emsg[(size_t)(e0base+e)*360 + o] = s * als[e*4 + o/24];
        }
      }
    }
  }
  // so2#1: Wl0[0] @ bA * rad -> bB
  if (r < 24) {
    float acc[4][4] = {};
    gemm44(acc, ws + OFF_WL0T + 0*9216 + o0, 96, bA + e0, 96);
    for (int i = 0; i < 4; ++i) {
      float4 rv = *(const float4*)(radb + (o0+i)*32 + e0);
      *(float4*)(bB + (o0+i)*32 + e0) =
        make_float4(acc[i][0]*rv.x, acc[i][1]*rv.y, acc[i][2]*rv.z, acc[i][3]*rv.w);
    }
  }
  __syncthreads();
  // LN (row2) + silu on bB
  ln_stats(bB, 96, bC, statA, statB, t, 1e-5f, 1.f/96.f);
  for (int idx = t; idx < 96*32; idx += 256) {
    int c = idx >> 5, e = idx & 31;
    bB[idx] = siluf((bB[idx]-statA[e])*statB[e]*ln_w0[192+c] + ln_b0[192+c]);
  }
  __syncthreads();
  // so2#2: Wl0[1] @ bB, * alpha -> bC
  if (r < 24) {
    float acc[4][4] = {};
    gemm44(acc, ws + OFF_WL0T + 1*9216 + o0, 96, bB + e0, 96);
    int head = o0 / 24;
    float al0 = als[(e0+0)*4 + head], al1 = als[(e0+1)*4 + head];
    float al2 = als[(e0+2)*4 + head], al3 = als[(e0+3)*4 + head];
    for (int i = 0; i < 4; ++i)
      *(float4*)(bC + (o0+i)*32 + e0) =
        make_float4(acc[i][0]*al0, acc[i][1]*al1, acc[i][2]*al2, acc[i][3]*al3);
  }
  __syncthreads();
  // destage
  if (!flags[lane_e]) {
    float* op = emsg + (size_t)(e0base+lane_e)*360;
    for (int k = 0; k < 3; ++k) {
      int q = g + 8*k;
      float4 v = { bC[(4*q+0)*32+lane_e], bC[(4*q+1)*32+lane_e],
                   bC[(4*q+2)*32+lane_e], bC[(4*q+3)*32+lane_e] };
      *(float4*)(op + 4*q) = v;
    }
  }
}

// ---------------- v1 chain ----------------
__global__ __launch_bounds__(256,3) void k_v1c(
    const float* __restrict__ edge_fea, const float* __restrict__ edge_vec,
    const float* __restrict__ D1g,
    const float* __restrict__ ln_w1, const float* __restrict__ r_b2,
    const int* __restrict__ edge_src, const int* __restrict__ edge_dst,
    const float* __restrict__ ws, float* __restrict__ emsg)
{
  __shared__ __align__(16) float ebuf[3*48*32];    // 4608
  __shared__ __align__(16) float msgb[3*48*32];    // 4608
  __shared__ __align__(16) float S[48*32];         // 1536 staging + pbuf
  __shared__ __align__(16) float radb[48*32];      // 1536
  __shared__ float D1s[32*9], G1s[32*9];
  __shared__ __align__(16) float als[128];
  __shared__ float statB[32];
  __shared__ int srcs[32], dsts[32], flags[32];
  const int t = threadIdx.x, lane_e = t & 31, g = t >> 5;
  const int e0base = blockIdx.x * 32;
  const int eq = t & 7, r = t >> 3, e0 = 4*eq;

  if (t < 32) {
    srcs[t] = edge_src[e0base+t]; dsts[t] = edge_dst[e0base+t];
    float vx = edge_vec[(e0base+t)*3+0], vy = edge_vec[(e0base+t)*3+1], vz = edge_vec[(e0base+t)*3+2];
    flags[t] = (vx*vx + vy*vy + vz*vz) < 1e-20f ? 1 : 0;
  }
  if (t >= 32 && t < 64) {
    int e = t - 32;
    *(float4*)(als + e*4) = *(const float4*)(ws + OFF_ALPHA + (size_t)(e0base+e)*4);
  }
  for (int idx = t; idx < 288; idx += 256) D1s[idx] = D1g[(size_t)e0base*9 + idx];
  // h1 -> ebuf rows 0..63
  for (int k = 0; k < 2; ++k) {
    int q = g + 8*k;
    float4 v = *(const float4*)(ws + OFF_H1 + (size_t)(e0base+lane_e)*64 + 4*q);
    ebuf[(4*q+0)*32+lane_e] = v.x; ebuf[(4*q+1)*32+lane_e] = v.y;
    ebuf[(4*q+2)*32+lane_e] = v.z; ebuf[(4*q+3)*32+lane_e] = v.w;
  }
  __syncthreads();
  for (int idx = t; idx < 288; idx += 256) {
    int e = idx/9, nn = (idx%9)/3, p = idx%3;
    float s = 0.f;
    for (int m = 0; m < 3; ++m) s += D1s[e*9+nn*3+m]*D1s[e*9+p*3+m];
    G1s[idx] = s;
  }
  // radial v1 (48 outs, cols 96..143) -> radb
  if (r < 24) {
    int oo = 2*r;
    float acc[2][4] = {};
    gemm24(acc, ws + OFF_RW2T + 96 + oo, 168, ebuf + e0, 64);
    for (int i = 0; i < 2; ++i) {
      float b = r_b2[96 + oo + i];
      *(float4*)(radb + (oo+i)*32 + e0) =
        make_float4(acc[i][0]+b, acc[i][1]+b, acc[i][2]+b, acc[i][3]+b);
    }
  }
  __syncthreads();
  // raw edge v1 -> msgb [m][c][e], LN (row1)
  {
    const float* ep = edge_fea + (size_t)(e0base+lane_e)*360 + 96;
    for (int k = 0; k < 5; ++k) {
      int q = g + 8*k;
      if (q < 36) {
        float4 v = *(const float4*)(ep + 4*q);
        float vv[4] = {v.x,v.y,v.z,v.w};
        for (int i = 0; i < 4; ++i) { int f = 4*q+i; msgb[((f%3)*48 + f/3)*32 + lane_e] = vv[i]; }
      }
    }
  }
  __syncthreads();
  vec_stats(msgb, 144, S, statB, t, 1e-5f, 1.f/48.f);
  for (int idx = t; idx < 4608; idx += 256) {
    int row = idx >> 5, e = idx & 31;
    msgb[idx] *= statB[e]*ln_w1[48 + (row % 48)];
  }
  __syncthreads();
  // message GEMM per m: [src|dst|edge] -> ebuf
  for (int m = 0; m < 3; ++m) {
    {
      const float* sp = ws + OFF_NODE_V1 + (size_t)srcs[lane_e]*144 + m*48;
      for (int k = 0; k < 2; ++k) {
        int q = g + 8*k;
        if (q < 12) {
          float4 a = *(const float4*)(sp + 4*q);
          S[(4*q+0)*32+lane_e] = a.x; S[(4*q+1)*32+lane_e] = a.y;
          S[(4*q+2)*32+lane_e] = a.z; S[(4*q+3)*32+lane_e] = a.w;
        }
      }
    }
    __syncthreads();
    float acc[2][4] = {};
    const int oo = 2*r;
    if (r < 24) gemm24(acc, ws + OFF_PREW1T + oo, 48, S + e0, 48);
    __syncthreads();
    {
      const float* dp = ws + OFF_NODE_V1 + (size_t)dsts[lane_e]*144 + m*48;
      for (int k = 0; k < 2; ++k) {
        int q = g + 8*k;
        if (q < 12) {
          float4 a = *(const float4*)(dp + 4*q);
          S[(4*q+0)*32+lane_e] = a.x; S[(4*q+1)*32+lane_e] = a.y;
          S[(4*q+2)*32+lane_e] = a.z; S[(4*q+3)*32+lane_e] = a.w;
        }
      }
    }
    __syncthreads();
    if (r < 24) {
      gemm24(acc, ws + OFF_PREW1T + 48*48 + oo, 48, S + e0, 48);
      gemm24(acc, ws + OFF_PREW1T + 96*48 + oo, 48, msgb + m*1536 + e0, 48);
      for (int i = 0; i < 2; ++i)
        *(float4*)(ebuf + m*1536 + (oo+i)*32 + e0) =
          make_float4(acc[i][0], acc[i][1], acc[i][2], acc[i][3]);
    }
    __syncthreads();
  }
  // onsite (rare): irreps_lin(message) directly to global
  {
    int f = flags[t & 31];
    int any = __syncthreads_or(f);
    if (any) {
      for (int idx = t; idx < 4608; idx += 256) {
        int e = idx & 31, row = idx >> 5, c = row % 48, nn = row / 48;
        if (flags[e]) {
          float s = 0.f;
          #pragma unroll 1
          for (int cc = 0; cc < 48; ++cc)
            s = fmaf(ws[OFF_WL1T + 2*2304 + cc*48 + c], ebuf[nn*1536 + cc*32 + e], s);
          emsg[(size_t)(e0base+e)*360 + 96 + c*3 + nn] = s * als[e*4 + c/12];
        }
      }
      __syncthreads();
    }
  }
  // rotate in: msgb[n] = sum_m D1[n,m]*ebuf[m]
  for (int idx = t; idx < 4608; idx += 256) {
    int e = idx & 31, row = idx >> 5, c = row % 48, nn = row / 48;
    float s = 0.f;
    for (int m = 0; m < 3; ++m) s = fmaf(D1s[e*9+nn*3+m], ebuf[m*1536 + c*32 + e], s);
    msgb[nn*1536 + c*32 + e] = s;
  }
  __syncthreads();
  // so2#1 * rad -> ebuf
  if (r < 24) {
    const int oo = 2*r;
    for (int nn = 0; nn < 3; ++nn) {
      float acc[2][4] = {};
      gemm24(acc, ws + OFF_WL1T + 0*2304 + oo, 48, msgb + nn*1536 + e0, 48);
      for (int i = 0; i < 2; ++i) {
        float4 rv = *(const float4*)(radb + (oo+i)*32 + e0);
        *(float4*)(ebuf + nn*1536 + (oo+i)*32 + e0) =
          make_float4(acc[i][0]*rv.x, acc[i][1]*rv.y, acc[i][2]*rv.z, acc[i][3]*rv.w);
      }
    }
  }
  __syncthreads();
  // LN (row2)
  vec_stats(ebuf, 144, S, statB, t, 1e-5f, 1.f/48.f);
  for (int idx = t; idx < 4608; idx += 256) {
    int row = idx >> 5, e = idx & 31;
    ebuf[idx] *= statB[e]*ln_w1[96 + (row % 48)];
  }
  __syncthreads();
  // G rotation -> msgb
  for (int idx = t; idx < 4608; idx += 256) {
    int e = idx & 31, row = idx >> 5, c = row % 48, nn = row / 48;
    float s = 0.f;
    for (int p = 0; p < 3; ++p) s = fmaf(G1s[e*9+nn*3+p], ebuf[p*1536 + c*32 + e], s);
    msgb[nn*1536 + c*32 + e] = s;
  }
  __syncthreads();
  // so2#2 -> ebuf
  if (r < 24) {
    const int oo = 2*r;
    for (int nn = 0; nn < 3; ++nn) {
      float acc[2][4] = {};
      gemm24(acc, ws + OFF_WL1T + 1*2304 + oo, 48, msgb + nn*1536 + e0, 48);
      for (int i = 0; i < 2; ++i)
        *(float4*)(ebuf + nn*1536 + (oo+i)*32 + e0) =
          make_float4(acc[i][0], acc[i][1], acc[i][2], acc[i][3]);
    }
  }
  __syncthreads();
  // rotate back * alpha -> msgb
  for (int idx = t; idx < 4608; idx += 256) {
    int e = idx & 31, row = idx >> 5, c = row % 48, nn = row / 48;
    float s = 0.f;
    for (int m = 0; m < 3; ++m) s = fmaf(D1s[e*9+m*3+nn], ebuf[m*1536 + c*32 + e], s);
    msgb[nn*1536 + c*32 + e] = s * als[e*4 + c/12];
  }
  __syncthreads();
  // destage
  if (!flags[lane_e]) {
    float* op = emsg + (size_t)(e0base+lane_e)*360 + 96;
    for (int k = 0; k < 5; ++k) {
      int q = g + 8*k;
      if (q < 36) {
        float4 v;
        float vv[4];
        for (int i = 0; i < 4; ++i) {
          int f = 4*q+i;
          vv[i] = msgb[((f%3)*48 + f/3)*32 + lane_e];
        }
        v = make_float4(vv[0], vv[1], vv[2], vv[3]);
        *(float4*)(op + 4*q) = v;
      }
    }
  }
}

// ---------------- v2 chain ----------------
__global__ __launch_bounds__(256,3) void k_v2c(
    const float* __restrict__ edge_fea, const float* __restrict__ edge_vec,
    const float* __restrict__ D2g,
    const float* __restrict__ ln_w2, const float* __restrict__ r_b2,
    const int* __restrict__ edge_src, const int* __restrict__ edge_dst,
    const float* __restrict__ ws, float* __restrict__ emsg)
{
  __shared__ __align__(16) float ebuf[5*24*32];    // 3840
  __shared__ __align__(16) float msgb[5*24*32];    // 3840
  __shared__ __align__(16) float S[2*24*32];       // 1536 staging + pbuf
  __shared__ __align__(16) float radb[24*32];      // 768
  __shared__ float D2s[32*25], G2s[32*25];
  __shared__ __align__(16) float als[128];
  __shared__ float statB[32];
  __shared__ int srcs[32], dsts[32], flags[32];
  const int t = threadIdx.x, lane_e = t & 31, g = t >> 5;
  const int e0base = blockIdx.x * 32;
  const int eq = t & 7, r = t >> 3, e0 = 4*eq;

  if (t < 32) {
    srcs[t] = edge_src[e0base+t]; dsts[t] = edge_dst[e0base+t];
    float vx = edge_vec[(e0base+t)*3+0], vy = edge_vec[(e0base+t)*3+1], vz = edge_vec[(e0base+t)*3+2];
    flags[t] = (vx*vx + vy*vy + vz*vz) < 1e-20f ? 1 : 0;
  }
  if (t >= 32 && t < 64) {
    int e = t - 32;
    *(float4*)(als + e*4) = *(const float4*)(ws + OFF_ALPHA + (size_t)(e0base+e)*4);
  }
  for (int idx = t; idx < 800; idx += 256) D2s[idx] = D2g[(size_t)e0base*25 + idx];
  for (int k = 0; k < 2; ++k) {
    int q = g + 8*k;
    float4 v = *(const float4*)(ws + OFF_H1 + (size_t)(e0base+lane_e)*64 + 4*q);
    ebuf[(4*q+0)*32+lane_e] = v.x; ebuf[(4*q+1)*32+lane_e] = v.y;
    ebuf[(4*q+2)*32+lane_e] = v.z; ebuf[(4*q+3)*32+lane_e] = v.w;
  }
  __syncthreads();
  for (int idx = t; idx < 800; idx += 256) {
    int e = idx/25, q = idx%25, nn = q/5, p = q%5;
    float s = 0.f;
    for (int m = 0; m < 5; ++m) s += D2s[e*25+nn*5+m]*D2s[e*25+p*5+m];
    G2s[idx] = s;
  }
  // radial v2 (24 outs, cols 144..167) -> radb
  if (r < 12) {
    int oo = 2*r;
    float acc[2][4] = {};
    gemm24(acc, ws + OFF_RW2T + 144 + oo, 168, ebuf + e0, 64);
    for (int i = 0; i < 2; ++i) {
      float b = r_b2[144 + oo + i];
      *(float4*)(radb + (oo+i)*32 + e0) =
        make_float4(acc[i][0]+b, acc[i][1]+b, acc[i][2]+b, acc[i][3]+b);
    }
  }
  __syncthreads();
  // raw edge v2 -> msgb [m][c][e], LN (row1)
  {
    const float* ep = edge_fea + (size_t)(e0base+lane_e)*360 + 240;
    for (int k = 0; k < 4; ++k) {
      int q = g + 8*k;
      if (q < 30) {
        float4 v = *(const float4*)(ep + 4*q);
        float vv[4] = {v.x,v.y,v.z,v.w};
        for (int i = 0; i < 4; ++i) { int f = 4*q+i; msgb[((f%5)*24 + f/5)*32 + lane_e] = vv[i]; }
      }
    }
  }
  __syncthreads();
  vec_stats(msgb, 120, S, statB, t, 1e-5f, 1.f/24.f);
  for (int idx = t; idx < 3840; idx += 256) {
    int row = idx >> 5, e = idx & 31;
    msgb[idx] *= statB[e]*ln_w2[24 + (row % 24)];
  }
  __syncthreads();
  // message GEMMs, m-pairs -> ebuf
  for (int mb = 0; mb < 5; mb += 2) {
    {
      for (int k = 0; k < 2; ++k) {
        int q = g + 8*k;
        if (q < 12) {
          int dm = q / 6, c4 = (q % 6) * 4;
          if (mb + dm < 5) {
            float4 a = *(const float4*)(ws + OFF_NODE_V2 + (size_t)srcs[lane_e]*120 + (mb+dm)*24 + c4);
            S[dm*768 + (c4+0)*32+lane_e] = a.x; S[dm*768 + (c4+1)*32+lane_e] = a.y;
            S[dm*768 + (c4+2)*32+lane_e] = a.z; S[dm*768 + (c4+3)*32+lane_e] = a.w;
          }
        }
      }
    }
    __syncthreads();
    float acc[2][4] = {};
    const int dm = r / 12, oc = r % 12, m = mb + dm, oo = 2*oc;
    if (r < 24 && m < 5)
      gemm24(acc, ws + OFF_PREW2T + oo, 24, S + dm*768 + e0, 24);
    __syncthreads();
    {
      for (int k = 0; k < 2; ++k) {
        int q = g + 8*k;
        if (q < 12) {
          int dm2 = q / 6, c4 = (q % 6) * 4;
          if (mb + dm2 < 5) {
            float4 a = *(const float4*)(ws + OFF_NODE_V2 + (size_t)dsts[lane_e]*120 + (mb+dm2)*24 + c4);
            S[dm2*768 + (c4+0)*32+lane_e] = a.x; S[dm2*768 + (c4+1)*32+lane_e] = a.y;
            S[dm2*768 + (c4+2)*32+lane_e] = a.z; S[dm2*768 + (c4+3)*32+lane_e] = a.w;
          }
        }
      }
    }
    __syncthreads();
    if (r < 24 && m < 5) {
      gemm24(acc, ws + OFF_PREW2T + 24*24 + oo, 24, S + dm*768 + e0, 24);
      gemm24(acc, ws + OFF_PREW2T + 48*24 + oo, 24, msgb + m*768 + e0, 24);
      for (int i = 0; i < 2; ++i)
        *(float4*)(ebuf + m*768 + (oo+i)*32 + e0) =
          make_float4(acc[i][0], acc[i][1], acc[i][2], acc[i][3]);
    }
    __syncthreads();
  }
  // onsite (rare)
  {
    int f = flags[t & 31];
    int any = __syncthreads_or(f);
    if (any) {
      for (int idx = t; idx < 3840; idx += 256) {
        int e = idx & 31, row = idx >> 5, c = row % 24, nn = row / 24;
        if (flags[e]) {
          float s = 0.f;
          #pragma unroll 1
          for (int cc = 0; cc < 24; ++cc)
            s = fmaf(ws[OFF_WL2T + 2*576 + cc*24 + c], ebuf[nn*768 + cc*32 + e], s);
          emsg[(size_t)(e0base+e)*360 + 240 + c*5 + nn] = s * als[e*4 + c/6];
        }
      }
      __syncthreads();
    }
  }
  // rotate in D2 -> msgb
  for (int idx = t; idx < 3840; idx += 256) {
    int e = idx & 31, row = idx >> 5, c = row % 24, nn = row / 24;
    float s = 0.f;
    for (int m = 0; m < 5; ++m) s = fmaf(D2s[e*25+nn*5+m], ebuf[m*768 + c*32 + e], s);
    msgb[nn*768 + c*32 + e] = s;
  }
  __syncthreads();
  // so2#1 * rad -> ebuf (nn pairs)
  if (r < 24) {
    const int dm = r / 12, oc = r % 12, oo = 2*oc;
    for (int nb = 0; nb < 5; nb += 2) {
      int nn = nb + dm;
      if (nn < 5) {
        float acc[2][4] = {};
        gemm24(acc, ws + OFF_WL2T + 0*576 + oo, 24, msgb + nn*768 + e0, 24);
        for (int i = 0; i < 2; ++i) {
          float4 rv = *(const float4*)(radb + (oo+i)*32 + e0);
          *(float4*)(ebuf + nn*768 + (oo+i)*32 + e0) =
            make_float4(acc[i][0]*rv.x, acc[i][1]*rv.y, acc[i][2]*rv.z, acc[i][3]*rv.w);
        }
      }
    }
  }
  __syncthreads();
  vec_stats(ebuf, 120, S, statB, t, 1e-5f, 1.f/24.f);
  for (int idx = t; idx < 3840; idx += 256) {
    int row = idx >> 5, e = idx & 31;
    ebuf[idx] *= statB[e]*ln_w2[48 + (row % 24)];
  }
  __syncthreads();
  // G2 rotation -> msgb
  for (int idx = t; idx < 3840; idx += 256) {
    int e = idx & 31, row = idx >> 5, c = row % 24, nn = row / 24;
    float s = 0.f;
    for (int p = 0; p < 5; ++p) s = fmaf(G2s[e*25+nn*5+p], ebuf[p*768 + c*32 + e], s);
    msgb[nn*768 + c*32 + e] = s;
  }
  __syncthreads();
  // so2#2 -> ebuf
  if (r < 24) {
    const int dm = r / 12, oc = r % 12, oo = 2*oc;
    for (int nb = 0; nb < 5; nb += 2) {
      int nn = nb + dm;
      if (nn < 5) {
        float acc[2][4] = {};
        gemm24(acc, ws + OFF_WL2T + 1*576 + oo, 24, msgb + nn*768 + e0, 24);
        for (int i = 0; i < 2; ++i)
          *(float4*)(ebuf + nn*768 + (oo+i)*32 + e0) =
            make_float4(acc[i][0], acc[i][1], acc[i][2], acc[i][3]);
      }
    }
  }
  __syncthreads();
  // rotate back * alpha -> msgb
  for (int idx = t; idx < 3840; idx += 256) {
    int e = idx & 31, row = idx >> 5, c = row % 24, nn = row / 24;
    float s = 0.f;
    for (int m = 0; m < 5; ++m) s = fmaf(D2s[e*25+m*5+nn], ebuf[m*768 + c*32 + e], s);
    msgb[nn*768 + c*32 + e] = s * als[e*4 + c/6];
  }
  __syncthreads();
  // destage
  if (!flags[lane_e]) {
    float* op = emsg + (size_t)(e0base+lane_e)*360 + 240;
    for (int k = 0; k < 4; ++k) {
      int q = g + 8*k;
      if (q < 30) {
        float vv[4];
        for (int i = 0; i < 4; ++i) {
          int f = 4*q+i;
          vv[i] = msgb[((f%5)*24 + f/5)*32 + lane_e];
        }
        *(float4*)(op + 4*q) = make_float4(vv[0], vv[1], vv[2], vv[3]);
      }
    }
  }
}

// ---------------- gather: node_msg = segment_sum(edge_msg) ----------------
__global__ __launch_bounds__(384) void k_gather(const float* __restrict__ emsg,
                                                const int* __restrict__ offs,
                                                const int* __restrict__ eidx,
                                                float* __restrict__ nodemsg)
{
  int n = blockIdx.x, t = threadIdx.x;
  if (t < 360) {
    int s0 = offs[n], s1 = offs[n+1];
    float s = 0.f;
    for (int k = s0; k < s1; ++k)
      s += emsg[(size_t)eidx[k]*360 + t];
    nodemsg[(size_t)n*360 + t] = s;
  }
}

// ---------------- unified output: irreps_lin(in1)*Wa + irreps_lin(in2)*Wb ----------------
__global__ __launch_bounds__(256,4) void k_out(
    const float* __restrict__ in1, const float* __restrict__ in2,
    const float* __restrict__ W0a, const float* __restrict__ W0b,
    const float* __restrict__ W1a, const float* __restrict__ W1b,
    const float* __restrict__ W2a, const float* __restrict__ W2b,
    float* __restrict__ outp, int Nrows)
{
  __shared__ __align__(16) float bA[144*32];
  __shared__ __align__(16) float bC[144*32];
  const int t = threadIdx.x, lane_e = t & 31, g = t >> 5;
  const int n0 = blockIdx.x * 32;
  const int n = n0 + lane_e;
  const bool valid = n < Nrows;
  const int eq = t & 7, r = t >> 3, e0 = 4*eq;

  // ---- scalars
  for (int k = 0; k < 3; ++k) {
    int q = g + 8*k;
    float4 a = valid ? *(const float4*)(in1 + (size_t)n*360 + 4*q) : make_float4(0,0,0,0);
    bA[(4*q+0)*32+lane_e] = a.x; bA[(4*q+1)*32+lane_e] = a.y;
    bA[(4*q+2)*32+lane_e] = a.z; bA[(4*q+3)*32+lane_e] = a.w;
  }
  __syncthreads();
  float accS[4][4] = {};
  const int o0 = 4*r;
  if (r < 24) gemm44(accS, W0a + o0, 96, bA + e0, 96);
  __syncthreads();
  for (int k = 0; k < 3; ++k) {
    int q = g + 8*k;
    float4 a = valid ? *(const float4*)(in2 + (size_t)n*360 + 4*q) : make_float4(0,0,0,0);
    bA[(4*q+0)*32+lane_e] = a.x; bA[(4*q+1)*32+lane_e] = a.y;
    bA[(4*q+2)*32+lane_e] = a.z; bA[(4*q+3)*32+lane_e] = a.w;
  }
  __syncthreads();
  if (r < 24) {
    gemm44(accS, W0b + o0, 96, bA + e0, 96);
    for (int i = 0; i < 4; ++i)
      *(float4*)(bC + (o0+i)*32 + e0) =
        make_float4(accS[i][0], accS[i][1], accS[i][2], accS[i][3]);
  }
  __syncthreads();
  for (int k = 0; k < 3; ++k) {
    int q = g + 8*k;
    if (valid) {
      float4 v = { bC[(4*q+0)*32+lane_e], bC[(4*q+1)*32+lane_e],
                   bC[(4*q+2)*32+lane_e], bC[(4*q+3)*32+lane_e] };
      *(float4*)(outp + (size_t)n*360 + 4*q) = v;
    }
  }
  __syncthreads();
  // ---- v1
  for (int k = 0; k < 5; ++k) {
    int q = g + 8*k;
    if (q < 36) {
      float4 a = valid ? *(const float4*)(in1 + (size_t)n*360 + 96 + 4*q) : make_float4(0,0,0,0);
      float av[4] = {a.x,a.y,a.z,a.w};
      for (int i = 0; i < 4; ++i) { int f = 4*q+i; bA[((f%3)*48 + f/3)*32 + lane_e] = av[i]; }
    }
  }
  __syncthreads();
  float accV[3][2][4] = {};
  const int oo = 2*r;
  if (r < 24)
    for (int nn = 0; nn < 3; ++nn)
      gemm24(accV[nn], W1a + oo, 48, bA + nn*1536 + e0, 48);
  __syncthreads();
  for (int k = 0; k < 5; ++k) {
    int q = g + 8*k;
    if (q < 36) {
      float4 a = valid ? *(const float4*)(in2 + (size_t)n*360 + 96 + 4*q) : make_float4(0,0,0,0);
      float av[4] = {a.x,a.y,a.z,a.w};
      for (int i = 0; i < 4; ++i) { int f = 4*q+i; bA[((f%3)*48 + f/3)*32 + lane_e] = av[i]; }
    }
  }
  __syncthreads();
  if (r < 24) {
    for (int nn = 0; nn < 3; ++nn) {
      gemm24(accV[nn], W1b + oo, 48, bA + nn*1536 + e0, 48);
      for (int i = 0; i < 2; ++i)
        *(float4*)(bC + (nn*48 + oo+i)*32 + e0) =
          make_float4(accV[nn][i][0], accV[nn][i][1], accV[nn][i][2], accV[nn][i][3]);
    }
  }
  __syncthreads();
  for (int k = 0; k < 5; ++k) {
    int q = g + 8*k;
    if (q < 36 && valid) {
      float vv[4];
      for (int i = 0; i < 4; ++i) { int f = 4*q+i; vv[i] = bC[((f%3)*48 + f/3)*32 + lane_e]; }
      *(float4*)(outp + (size_t)n*360 + 96 + 4*q) = make_float4(vv[0], vv[1], vv[2], vv[3]);
    }
  }
  __syncthreads();
  // ---- v2
  for (int k = 0; k < 4; ++k) {
    int q = g + 8*k;
    if (q < 30) {
      float4 a = valid ? *(const float4*)(in1 + (size_t)n*360 + 240 + 4*q) : make_float4(0,0,0,0);
      float av[4] = {a.x,a.y,a.z,a.w};
      for (int i = 0; i < 4; ++i) { int f = 4*q+i; bA[((f%5)*24 + f/5)*32 + lane_e] = av[i]; }
    }
  }
  __syncthreads();
  float accW[3][2][4] = {};
  const int dm = r / 12, oc = r % 12, o2 = 2*oc;
  if (r < 24)
    for (int nb = 0; nb < 5; nb += 2) {
      int nn = nb + dm;
      if (nn < 5) gemm24(accW[nb>>1], W2a + o2, 24, bA + nn*768 + e0, 24);
    }
  __syncthreads();
  for (int k = 0; k < 4; ++k) {
    int q = g + 8*k;
    if (q < 30) {
      float4 a = valid ? *(const float4*)(in2 + (size_t)n*360 + 240 + 4*q) : make_float4(0,0,0,0);
      float av[4] = {a.x,a.y,a.z,a.w};
      for (int i = 0; i < 4; ++i) { int f = 4*q+i; bA[((f%5)*24 + f/5)*32 + lane_e] = av[i]; }
    }
  }
  __syncthreads();
  if (r < 24) {
    for (int nb = 0; nb < 5; nb += 2) {
      int nn = nb + dm;
      if (nn < 5) {
        gemm24(accW[nb>>1], W2b + o2, 24, bA + nn*768 + e0, 24);
        for (int i = 0; i < 2; ++i)
          *(float4*)(bC + (nn*24 + o2+i)*32 + e0) =
            make_float4(accW[nb>>1][i][0], accW[nb>>1][i][1], accW[nb>>1][i][2], accW[nb>>1][i][3]);
      }
    }
  }
  __syncthreads();
  for (int k = 0; k < 4; ++k) {
    int q = g + 8*k;
    if (q < 30 && valid) {
      float vv[4];
      for (int i = 0; i < 4; ++i) { int f = 4*q+i; vv[i] = bC[((f%5)*24 + f/5)*32 + lane_e]; }
      *(float4*)(outp + (size_t)n*360 + 240 + 4*q) = make_float4(vv[0], vv[1], vv[2], vv[3]);
    }
  }
}

extern "C" void kernel_launch(void* const* d_in, const int* in_sizes, int n_in,
                              void* d_out, int out_size, void* d_ws, size_t ws_size,
                              hipStream_t stream) {
  (void)in_sizes; (void)n_in; (void)out_size; (void)ws_size;
  const float* node_fea = (const float*)d_in[0];
  const float* edge_fea = (const float*)d_in[1];
  const float* ele      = (const float*)d_in[3];
  const float* edge_vec = (const float*)d_in[4];
  const float* D1       = (const float*)d_in[5];
  const float* D2       = (const float*)d_in[6];
  const float* Wl0      = (const float*)d_in[7];
  const float* Wl1      = (const float*)d_in[8];
  const float* Wl2      = (const float*)d_in[9];
  const float* preW0    = (const float*)d_in[10];
  const float* preW1    = (const float*)d_in[11];
  const float* preW2    = (const float*)d_in[12];
  const float* ln_w0    = (const float*)d_in[13];
  const float* ln_b0    = (const float*)d_in[14];
  const float* ln_w1    = (const float*)d_in[15];
  const float* ln_w2    = (const float*)d_in[16];
  const float* qk_W1    = (const float*)d_in[17];
  const float* qk_b1    = (const float*)d_in[18];
  const float* qk_lnw   = (const float*)d_in[19];
  const float* qk_lnb   = (const float*)d_in[20];
  const float* qk_W2    = (const float*)d_in[21];
  const float* qk_b2    = (const float*)d_in[22];
  const float* a_W1     = (const float*)d_in[23];
  const float* a_b1     = (const float*)d_in[24];
  const float* a_ln1w   = (const float*)d_in[25];
  const float* a_ln1b   = (const float*)d_in[26];
  const float* a_W2     = (const float*)d_in[27];
  const float* a_b2     = (const float*)d_in[28];
  const float* a_ln2w   = (const float*)d_in[29];
  const float* a_ln2b   = (const float*)d_in[30];
  const float* a_W3     = (const float*)d_in[31];
  const float* a_b3     = (const float*)d_in[32];
  const float* r_W1     = (const float*)d_in[33];
  const float* r_b1     = (const float*)d_in[34];
  const float* r_W2     = (const float*)d_in[35];
  const float* r_b2     = (const float*)d_in[36];
  const int* edge_src   = (const int*)d_in[37];
  const int* edge_dst   = (const int*)d_in[38];
  float* ws  = (float*)d_ws;
  int*   wsi = (int*)d_ws;
  float* out = (float*)d_out;
  float* emsg = out + (size_t)N_NODES*360;   // edge region of out used as edge_msg scratch

  k_prep<<<dim3(33), dim3(256), 0, stream>>>(preW0, preW1, preW2, Wl0, Wl1, Wl2,
                                             qk_W1, qk_W2, a_W1, a_W2, a_W3, r_W1, r_W2, ws);
  // zero deg + cur (contiguous)
  hipMemsetAsync((char*)d_ws + (size_t)OFFI_DEG*4, 0, 20000*4, stream);
  k_hist<<<dim3(625), dim3(256), 0, stream>>>(edge_dst, wsi + OFFI_DEG);
  k_scan<<<dim3(1), dim3(256), 0, stream>>>(wsi + OFFI_DEG, wsi + OFFI_OFFS);
  k_scatter<<<dim3(625), dim3(256), 0, stream>>>(edge_dst, wsi + OFFI_OFFS,
                                                 wsi + OFFI_CUR, wsi + OFFI_EIDX);
  k_node<<<dim3((N_NODES+31)/32), dim3(256), 0, stream>>>(node_fea, ln_w0, ln_b0, ln_w1, ln_w2,
                                                          qk_b1, qk_lnw, qk_lnb, qk_b2, ws);
  k_alpha<<<dim3(N_EDGES/32), dim3(256), 0, stream>>>(ele, r_b1, a_b1, a_ln1w, a_ln1b,
                                                      a_b2, a_ln2w, a_ln2b, a_b3,
                                                      edge_src, edge_dst, ws);
  k_sc<<<dim3(N_EDGES/32), dim3(256), 0, stream>>>(edge_fea, edge_vec, ln_w0, ln_b0, r_b2,
                                                   edge_src, edge_dst, ws, emsg);
  k_v1c<<<dim3(N_EDGES/32), dim3(256), 0, stream>>>(edge_fea, edge_vec, D1, ln_w1, r_b2,
                                                    edge_src, edge_dst, ws, emsg);
  k_v2c<<<dim3(N_EDGES/32), dim3(256), 0, stream>>>(edge_fea, edge_vec, D2, ln_w2, r_b2,
                                                    edge_src, edge_dst, ws, emsg);
  k_gather<<<dim3(N_NODES), dim3(384), 0, stream>>>(emsg, wsi + OFFI_OFFS,
                                                    wsi + OFFI_EIDX, ws + OFF_NODEMSG);
  // edge_out: in-place over emsg
  k_out<<<dim3(N_EDGES/32), dim3(256), 0, stream>>>(emsg, edge_fea,
      ws + OFF_WL0T + 4*9216, ws + OFF_WL0T + 6*9216,
      ws + OFF_WL1T + 4*2304, ws + OFF_WL1T + 6*2304,
      ws + OFF_WL2T + 4*576,  ws + OFF_WL2T + 6*576,
      emsg, N_EDGES);
  // node_out
  k_out<<<dim3((N_NODES+31)/32), dim3(256), 0, stream>>>(ws + OFF_NODEMSG, node_fea,
      ws + OFF_WL0T + 3*9216, ws + OFF_WL0T + 5*9216,
      ws + OFF_WL1T + 3*2304, ws + OFF_WL1T + 5*2304,
      ws + OFF_WL2T + 3*576,  ws + OFF_WL2T + 5*576,
      out, N_NODES);
}